// Round 2
// baseline (1593.762 us; speedup 1.0000x reference)
//
#include <hip/hip_runtime.h>
#include <hip/hip_bf16.h>

// LightGCN forward on MI355X.
// R7: sort-based graph build. R6 falsified "edge streams evict dirty col
//     lines" (nt loads: WRITE 322->317MB, no change). New theory: the random
//     scatter itself lacks temporal locality -- each 64B col sector needs ~16
//     writes spread over the whole 262us kernel; lines get evicted partial and
//     write-allocate-refetched repeatedly (FETCH ~4x, WRITE ~13x region size).
//     Fix: radix-partition pairs into 587 dst-buckets (41KB col each), then
//     one block per bucket scatters -- every line filled within one block
//     lifetime -> written back once. Side effects: edges read 1x (not 8x),
//     hist/dinv/scan/bounds kernels folded into the bucketed build; pair
//     staging (48MB) aliases za/zb (dead until init_z). Also reverted R6's
//     zn nt-store (zn is re-read by next pull from L2 -- nt evicted it;
//     likely the 1347->1386 regression).

#define WAVE 64
#define NBMAX 640   // max dst buckets (covers N <= 640*256 at shift=8)
#define BCAP 8      // LDS-staged pairs per bucket (64B flush granularity)

typedef int nt_int4 __attribute__((ext_vector_type(4)));

// --- pass 1: per-bucket pair counts (edges read once) --------------------
__global__ __launch_bounds__(256) void bhist_kernel(const int* __restrict__ ue,
                                                    const int* __restrict__ ie,
                                                    int* __restrict__ bcnt,
                                                    int E, int nu, int NB, int shift,
                                                    int gpb, int NG) {
    __shared__ int lh[NBMAX];
    int tid = threadIdx.x;
    for (int b = tid; b < NB; b += 256) lh[b] = 0;
    __syncthreads();
    int g0 = blockIdx.x * gpb;
    int g1 = min(g0 + gpb, NG);
    for (int g = g0 + tid; g < g1; g += 256) {
        int e0 = g * 4;
        if (e0 + 3 < E) {
            nt_int4 u = __builtin_nontemporal_load((const nt_int4*)(ue + e0));
            nt_int4 v = __builtin_nontemporal_load((const nt_int4*)(ie + e0));
            atomicAdd(&lh[(nu + v.x) >> shift], 1); atomicAdd(&lh[u.x >> shift], 1);
            atomicAdd(&lh[(nu + v.y) >> shift], 1); atomicAdd(&lh[u.y >> shift], 1);
            atomicAdd(&lh[(nu + v.z) >> shift], 1); atomicAdd(&lh[u.z >> shift], 1);
            atomicAdd(&lh[(nu + v.w) >> shift], 1); atomicAdd(&lh[u.w >> shift], 1);
        } else {
            for (int e = e0; e < E; ++e) {
                atomicAdd(&lh[(nu + ie[e]) >> shift], 1);
                atomicAdd(&lh[ue[e] >> shift], 1);
            }
        }
    }
    __syncthreads();
    for (int b = tid; b < NB; b += 256) if (lh[b]) atomicAdd(&bcnt[b], lh[b]);
}

// --- pass 2: exclusive scan over NB bucket counts ------------------------
__global__ __launch_bounds__(1024) void bscan_kernel(const int* __restrict__ bcnt,
                                                     int* __restrict__ pbase,
                                                     int* __restrict__ pcur, int NB) {
    __shared__ int wsum[16];
    int t = threadIdx.x;
    int v0 = (t < NB) ? bcnt[t] : 0;
    int lane = t & 63, w = t >> 6;
    int v = v0;
    #pragma unroll
    for (int d = 1; d < 64; d <<= 1) {
        int o = __shfl_up(v, d, 64);
        if (lane >= d) v += o;
    }
    if (lane == 63) wsum[w] = v;
    __syncthreads();
    if (t == 0) {
        int r = 0;
        #pragma unroll
        for (int k = 0; k < 16; ++k) { int s = wsum[k]; wsum[k] = r; r += s; }
    }
    __syncthreads();
    int excl = (v - v0) + wsum[w];
    if (t < NB) { pbase[t] = excl; pcur[t] = excl; }
}

// --- pass 3: partition pairs into bucket-contiguous staging --------------
// LDS-staged: BCAP pairs per bucket, flushed as 64B runs at the bucket's
// write frontier (587 frontiers ~ 75KB dirty -> L2-resident, written once).
// Overflow within a round falls back to a direct 8B store (correct for any
// skew; rare for uniform dst).
__global__ __launch_bounds__(256) void part_kernel(const int* __restrict__ ue,
                                                   const int* __restrict__ ie,
                                                   int* __restrict__ pcur,
                                                   int2* __restrict__ pairs,
                                                   int E, int nu, int NB, int shift,
                                                   int gpb, int NG) {
    __shared__ int2 slot[NBMAX * BCAP];
    __shared__ int lcnt[NBMAX];
    int tid = threadIdx.x;
    for (int b = tid; b < NB; b += 256) lcnt[b] = 0;
    __syncthreads();
    int g0 = blockIdx.x * gpb;
    int g1 = min(g0 + gpb, NG);
    for (int g = g0; g < g1; g += 256) {   // block-synchronous rounds
        int gg = g + tid;
        int2 pr[8]; int np = 0;
        if (gg < g1) {
            int e0 = gg * 4;
            if (e0 + 3 < E) {
                nt_int4 u = __builtin_nontemporal_load((const nt_int4*)(ue + e0));
                nt_int4 v = __builtin_nontemporal_load((const nt_int4*)(ie + e0));
                pr[np++] = make_int2(nu + v.x, u.x); pr[np++] = make_int2(u.x, nu + v.x);
                pr[np++] = make_int2(nu + v.y, u.y); pr[np++] = make_int2(u.y, nu + v.y);
                pr[np++] = make_int2(nu + v.z, u.z); pr[np++] = make_int2(u.z, nu + v.z);
                pr[np++] = make_int2(nu + v.w, u.w); pr[np++] = make_int2(u.w, nu + v.w);
            } else {
                for (int e = e0; e < E; ++e) {
                    pr[np++] = make_int2(nu + ie[e], ue[e]);
                    pr[np++] = make_int2(ue[e], nu + ie[e]);
                }
            }
        }
        for (int i = 0; i < np; ++i) {
            int bb = pr[i].x >> shift;
            int pos = atomicAdd(&lcnt[bb], 1);
            if (pos < BCAP) slot[bb * BCAP + pos] = pr[i];
            else { int gp = atomicAdd(&pcur[bb], 1); pairs[gp] = pr[i]; }
        }
        __syncthreads();
        for (int bb = tid; bb < NB; bb += 256) {
            int nn = min(lcnt[bb], BCAP);
            if (nn == BCAP) {
                int base = atomicAdd(&pcur[bb], BCAP);
                #pragma unroll
                for (int i = 0; i < BCAP; ++i) pairs[base + i] = slot[bb * BCAP + i];
                lcnt[bb] = 0;
            } else {
                lcnt[bb] = nn;   // clamp any overflow count (extras went direct)
            }
        }
        __syncthreads();
    }
    // final partial flush
    for (int bb = tid; bb < NB; bb += 256) {
        int nn = min(lcnt[bb], BCAP);
        if (nn > 0) {
            int base = atomicAdd(&pcur[bb], nn);
            for (int i = 0; i < nn; ++i) pairs[base + i] = slot[bb * BCAP + i];
        }
    }
}

// --- pass 4: per-bucket CSR build (deg hist + local scan + scatter) ------
// One block per bucket. Writes offs/dinv/drt for its node range and col for
// its contiguous ~41KB col window -- all writes temporally clustered.
// Second pairs read is L2-hot (bucket pairs ~82KB, read twice back-to-back).
__global__ __launch_bounds__(256) void build_kernel(const int2* __restrict__ pairs,
                                                    const int* __restrict__ pbase,
                                                    const int* __restrict__ pcur,
                                                    int* __restrict__ offs,
                                                    float* __restrict__ dinv,
                                                    float* __restrict__ drt,
                                                    int* __restrict__ col,
                                                    int N, int shift, int NB, int twoE) {
    __shared__ int dcnt[512];
    __shared__ int ex[512];
    __shared__ int cur[512];
    int b = blockIdx.x, tid = threadIdx.x;
    int lo = b << shift;
    int n = min(1 << shift, N - lo);
    for (int i = tid; i < 512; i += 256) dcnt[i] = 0;
    __syncthreads();
    int pb = pbase[b];
    int cnt = pcur[b] - pb;
    for (int i = tid; i < cnt; i += 256) {
        int2 pr = pairs[pb + i];
        atomicAdd(&dcnt[pr.x - lo], 1);
    }
    __syncthreads();
    // exclusive scan of dcnt[0..512) by wave 0 (8 serial per lane + wave scan)
    if (tid < 64) {
        int base = tid * 8;
        int loc[8]; int s = 0;
        #pragma unroll
        for (int k = 0; k < 8; ++k) { loc[k] = s; s += dcnt[base + k]; }
        int v = s;
        #pragma unroll
        for (int d = 1; d < 64; d <<= 1) {
            int o = __shfl_up(v, d, 64);
            if (tid >= d) v += o;
        }
        int excl = v - s;
        #pragma unroll
        for (int k = 0; k < 8; ++k) ex[base + k] = excl + loc[k];
    }
    __syncthreads();
    for (int i = tid; i < n; i += 256) {
        int c = pb + ex[i];
        cur[i] = c;
        offs[lo + i] = c;
        int d = dcnt[i];
        dinv[lo + i] = (d > 0) ? rsqrtf((float)d) : 0.0f;
        drt[lo + i]  = (d > 0) ? sqrtf((float)d)  : 0.0f;
    }
    if (b == NB - 1 && tid == 0) offs[N] = twoE;
    __syncthreads();
    for (int i = tid; i < cnt; i += 256) {
        int2 pr = pairs[pb + i];
        int p = atomicAdd(&cur[pr.x - lo], 1);
        col[p] = pr.y;
    }
}

// --- batch-node marking / compaction -------------------------------------
__global__ void mark_kernel(const int* __restrict__ users, const int* __restrict__ items,
                            int* __restrict__ flag, int B, int nu) {
    int b = blockIdx.x * blockDim.x + threadIdx.x;
    if (b < B) {
        flag[users[b]] = 1;
        flag[nu + items[b]] = 1;
    }
}

__global__ void compact_kernel(const int* __restrict__ flag, int* __restrict__ list,
                               int* __restrict__ cnt, int N) {
    int n = blockIdx.x * blockDim.x + threadIdx.x;
    if (n < N && flag[n]) {
        int pos = atomicAdd(cnt, 1);
        list[pos] = n;
    }
}

__global__ void init_z_kernel(const float* __restrict__ Gu, const float* __restrict__ Gi,
                              const float* __restrict__ dinv,
                              float* __restrict__ z, int nuQ, int totQ) {
    int i = blockIdx.x * blockDim.x + threadIdx.x;  // float4 slots
    if (i < totQ) {
        const float4* src = (i < nuQ) ? (const float4*)Gu : (const float4*)Gi;
        int j = (i < nuQ) ? i : i - nuQ;
        float4 a = src[j];
        float w = dinv[i >> 4];
        a.x *= w; a.y *= w; a.z *= w; a.w *= w;
        ((float4*)z)[i] = a;
    }
}

__global__ void init_bacc_kernel(const float* __restrict__ Gu, const float* __restrict__ Gi,
                                 const int* __restrict__ users, const int* __restrict__ items,
                                 float* __restrict__ baccU, float* __restrict__ baccI, int B) {
    int id = blockIdx.x * blockDim.x + threadIdx.x;  // B*16 float4 slots
    if (id < B * 16) {
        int b = id >> 4, q = id & 15;
        ((float4*)baccU)[id] = ((const float4*)Gu)[(size_t)users[b] * 16 + q];
        ((float4*)baccI)[id] = ((const float4*)Gi)[(size_t)items[b] * 16 + q];
    }
}

// One wave per destination row. z_next[r] = dinv[r]^2 * sum_{c in N(r)} z[c].
__global__ __launch_bounds__(256) void pull_kernel(const float* __restrict__ z,
                                                   float* __restrict__ zn,
                                                   const int* __restrict__ offs,
                                                   const int* __restrict__ col,
                                                   const float* __restrict__ dinv,
                                                   const int* __restrict__ rows,
                                                   const int* __restrict__ n_ptr, int N) {
    int wid = (blockIdx.x * blockDim.x + threadIdx.x) >> 6;
    int lane = threadIdx.x & 63;
    int nrows = rows ? *n_ptr : N;
    if (wid >= nrows) return;
    int r = rows ? rows[wid] : wid;
    int s = offs[r], e = offs[r + 1];
    float acc0 = 0.0f, acc1 = 0.0f;
    for (int base = s; base < e; base += 64) {
        int idx = base + lane;
        int c = (idx < e) ? __builtin_nontemporal_load(col + idx) : 0;
        int n = min(64, e - base);
        int j = 0;
        for (; j + 4 <= n; j += 4) {
            int c0 = __shfl(c, j),     c1 = __shfl(c, j + 1);
            int c2 = __shfl(c, j + 2), c3 = __shfl(c, j + 3);
            float v0 = z[(size_t)c0 * WAVE + lane];
            float v1 = z[(size_t)c1 * WAVE + lane];
            float v2 = z[(size_t)c2 * WAVE + lane];
            float v3 = z[(size_t)c3 * WAVE + lane];
            acc0 += v0 + v1;
            acc1 += v2 + v3;
        }
        for (; j < n; ++j) {
            int cj = __shfl(c, j);
            acc0 += z[(size_t)cj * WAVE + lane];
        }
    }
    float w = dinv[r];
    zn[(size_t)r * WAVE + lane] = w * w * (acc0 + acc1);
}

__global__ void gather_acc_kernel(const float* __restrict__ zn,
                                  const float* __restrict__ drt,
                                  const int* __restrict__ users, const int* __restrict__ items,
                                  float* __restrict__ baccU, float* __restrict__ baccI,
                                  int B, int nu) {
    int id = blockIdx.x * blockDim.x + threadIdx.x;  // B*16 float4 slots
    if (id < B * 16) {
        int b = id >> 4, q = id & 15;
        int u = users[b], it = nu + items[b];
        float wu = drt[u], wi = drt[it];
        float4 a = ((float4*)baccU)[id];
        float4 v = ((const float4*)zn)[(size_t)u * 16 + q];
        a.x += wu * v.x; a.y += wu * v.y; a.z += wu * v.z; a.w += wu * v.w;
        ((float4*)baccU)[id] = a;
        float4 c = ((float4*)baccI)[id];
        float4 d = ((const float4*)zn)[(size_t)it * 16 + q];
        c.x += wi * d.x; c.y += wi * d.y; c.z += wi * d.z; c.w += wi * d.w;
        ((float4*)baccI)[id] = c;
    }
}

// LDS-tiled fp32 GEMM + fused epilogue.
// Block: 64 batch-rows x 64 outputs, 256 threads, 4x4 reg tile/thread.
__global__ __launch_bounds__(256) void proj_out_kernel(const float* __restrict__ baccU,
                                                       const float* __restrict__ baccI,
                                                       const float* __restrict__ Tu,
                                                       const float* __restrict__ F,
                                                       const float* __restrict__ W,
                                                       const float* __restrict__ bvec,
                                                       const int* __restrict__ users,
                                                       const int* __restrict__ items,
                                                       float* __restrict__ out,
                                                       int B, float invL) {
    const int FEATn = 1024;
    __shared__ float Ft[2][32][64];
    __shared__ float Wt[2][32][64];

    int tid = threadIdx.x;
    int tx = tid & 15;        // col group (4 cols)
    int ty = tid >> 4;        // row group (4 rows)
    int r0 = blockIdx.x * 64;

    int lr = tid >> 2;                       // 0..63
    int lq = tid & 3;                        // quad group: local kk 4*lq and 4*lq+16
    int frow = min(r0 + lr, B - 1);
    const float* Fp = F + (size_t)items[frow] * FEATn + lq * 4;
    const float* Wp = W + (size_t)lr * FEATn + lq * 4;

    float4 fa0 = *(const float4*)(Fp);
    float4 fa1 = *(const float4*)(Fp + 16);
    float4 wa0 = *(const float4*)(Wp);
    float4 wa1 = *(const float4*)(Wp + 16);

    float acc[4][4] = {};

    for (int kt = 0; kt < 32; ++kt) {
        int buf = kt & 1;
        #pragma unroll
        for (int i = 0; i < 4; ++i) {
            Ft[buf][lq * 4 + i][lr]      = ((const float*)&fa0)[i];
            Ft[buf][lq * 4 + 16 + i][lr] = ((const float*)&fa1)[i];
            Wt[buf][lq * 4 + i][lr]      = ((const float*)&wa0)[i];
            Wt[buf][lq * 4 + 16 + i][lr] = ((const float*)&wa1)[i];
        }
        __syncthreads();
        if (kt < 31) {
            const float* fp = Fp + (kt + 1) * 32;
            const float* wp = Wp + (kt + 1) * 32;
            fa0 = *(const float4*)(fp);
            fa1 = *(const float4*)(fp + 16);
            wa0 = *(const float4*)(wp);
            wa1 = *(const float4*)(wp + 16);
        }
        #pragma unroll 8
        for (int kk = 0; kk < 32; ++kk) {
            float4 a = *(const float4*)&Ft[buf][kk][ty * 4];
            float4 b = *(const float4*)&Wt[buf][kk][tx * 4];
            acc[0][0] = fmaf(a.x, b.x, acc[0][0]);
            acc[0][1] = fmaf(a.x, b.y, acc[0][1]);
            acc[0][2] = fmaf(a.x, b.z, acc[0][2]);
            acc[0][3] = fmaf(a.x, b.w, acc[0][3]);
            acc[1][0] = fmaf(a.y, b.x, acc[1][0]);
            acc[1][1] = fmaf(a.y, b.y, acc[1][1]);
            acc[1][2] = fmaf(a.y, b.z, acc[1][2]);
            acc[1][3] = fmaf(a.y, b.w, acc[1][3]);
            acc[2][0] = fmaf(a.z, b.x, acc[2][0]);
            acc[2][1] = fmaf(a.z, b.y, acc[2][1]);
            acc[2][2] = fmaf(a.z, b.z, acc[2][2]);
            acc[2][3] = fmaf(a.z, b.w, acc[2][3]);
            acc[3][0] = fmaf(a.w, b.x, acc[3][0]);
            acc[3][1] = fmaf(a.w, b.y, acc[3][1]);
            acc[3][2] = fmaf(a.w, b.z, acc[3][2]);
            acc[3][3] = fmaf(a.w, b.w, acc[3][3]);
        }
    }

    float4 bb = *(const float4*)(bvec + tx * 4);
    float L2 = invL * invL;
    float res[4];
    #pragma unroll
    for (int r = 0; r < 4; ++r) {
        int gr = min(r0 + ty * 4 + r, B - 1);
        float pb0 = acc[r][0] + bb.x;
        float pb1 = acc[r][1] + bb.y;
        float pb2 = acc[r][2] + bb.z;
        float pb3 = acc[r][3] + bb.w;
        float s = pb0 * pb0 + pb1 * pb1 + pb2 * pb2 + pb3 * pb3;
        #pragma unroll
        for (int d = 1; d < 16; d <<= 1) s += __shfl_xor(s, d, 64);
        float inv = 1.0f / fmaxf(sqrtf(s), 1e-12f);
        int u = users[gr];
        float4 tu = *(const float4*)(Tu + (size_t)u * WAVE + tx * 4);
        float4 gu = *(const float4*)(baccU + (size_t)gr * WAVE + tx * 4);
        float4 gi = *(const float4*)(baccI + (size_t)gr * WAVE + tx * 4);
        float dsum = L2 * (gu.x * gi.x + gu.y * gi.y + gu.z * gi.z + gu.w * gi.w)
                   + inv * (tu.x * pb0 + tu.y * pb1 + tu.z * pb2 + tu.w * pb3);
        #pragma unroll
        for (int d = 1; d < 16; d <<= 1) dsum += __shfl_xor(dsum, d, 64);
        res[r] = dsum;
    }
    if (tx == 0) {
        #pragma unroll
        for (int r = 0; r < 4; ++r) {
            int gr = r0 + ty * 4 + r;
            if (gr < B) out[gr] = res[r];
        }
    }
}

extern "C" void kernel_launch(void* const* d_in, const int* in_sizes, int n_in,
                              void* d_out, int out_size, void* d_ws, size_t ws_size,
                              hipStream_t stream) {
    const float* Gu = (const float*)d_in[0];
    const float* Gi = (const float*)d_in[1];
    const float* Tu = (const float*)d_in[2];
    const float* F  = (const float*)d_in[3];
    const float* W  = (const float*)d_in[4];
    const float* bv = (const float*)d_in[5];
    const int* ue    = (const int*)d_in[6];
    const int* ie    = (const int*)d_in[7];
    const int* users = (const int*)d_in[8];
    const int* items = (const int*)d_in[9];
    float* out = (float*)d_out;

    const int K  = 64;
    const int nu = in_sizes[0] / K;
    const int ni = in_sizes[1] / K;
    const int N  = nu + ni;
    const int E  = in_sizes[6];
    const int B  = in_sizes[8];

    char* p = (char*)d_ws;
    auto alloc = [&](size_t bytes) -> void* {
        void* r = (void*)p;
        p += (bytes + 255) & ~(size_t)255;
        return r;
    };
    float* dinv   = (float*)alloc((size_t)N * 4);
    float* drt    = (float*)alloc((size_t)N * 4);
    int*   offs   = (int*)  alloc((size_t)(N + 1) * 4);
    int*   flags  = (int*)  alloc((size_t)N * 4);
    int*   col    = (int*)  alloc((size_t)2 * E * 4);
    float* za     = (float*)alloc((size_t)N * K * 4);
    float* zb     = (float*)alloc((size_t)N * K * 4);
    float* baccU  = (float*)alloc((size_t)B * K * 4);
    float* baccI  = (float*)alloc((size_t)B * K * 4);
    int*   list   = (int*)  alloc((size_t)2 * B * 4);
    int*   cnt    = (int*)  alloc(256);
    int*   bcnt   = (int*)  alloc((size_t)NBMAX * 4);
    int*   pbase  = (int*)  alloc((size_t)NBMAX * 4);
    int*   pcur   = (int*)  alloc((size_t)NBMAX * 4);

    // bucket geometry: 256 nodes/bucket (shift 8) for this problem size
    int shift = 8;
    while (((N + (1 << shift) - 1) >> shift) > NBMAX) ++shift;
    const int NB = (N + (1 << shift) - 1) >> shift;

    // pair staging (2E int2 = 48MB) aliases za+zb (76.8MB): pairs are dead
    // before init_z writes za / pull writes zb.
    int2* pairs = (int2*)za;

    const int NG  = (E + 3) / 4;          // int4 edge groups
    const int gpb = (NG + 255) / 256;     // groups per block (256 blocks)

    // graph build (edges read once per pass; all scatters bucket-localized)
    hipMemsetAsync(bcnt, 0, (size_t)NB * 4, stream);
    bhist_kernel<<<256, 256, 0, stream>>>(ue, ie, bcnt, E, nu, NB, shift, gpb, NG);
    bscan_kernel<<<1, 1024, 0, stream>>>(bcnt, pbase, pcur, NB);
    part_kernel<<<256, 256, 0, stream>>>(ue, ie, pcur, pairs, E, nu, NB, shift, gpb, NG);
    build_kernel<<<NB, 256, 0, stream>>>(pairs, pbase, pcur, offs, dinv, drt, col,
                                         N, shift, NB, 2 * E);

    // batch-node list
    hipMemsetAsync(flags, 0, (size_t)N * 4, stream);
    hipMemsetAsync(cnt, 0, 4, stream);
    mark_kernel<<<(B + 255) / 256, 256, 0, stream>>>(users, items, flags, B, nu);
    compact_kernel<<<(N + 255) / 256, 256, 0, stream>>>(flags, list, cnt, N);

    // init
    int totQ = N * K / 4, nuQ = nu * K / 4;
    init_z_kernel<<<(totQ + 255) / 256, 256, 0, stream>>>(Gu, Gi, dinv, za, nuQ, totQ);
    init_bacc_kernel<<<(B * 16 + 255) / 256, 256, 0, stream>>>(Gu, Gi, users, items,
                                                               baccU, baccI, B);

    // layer 1 (full)
    pull_kernel<<<(N + 3) / 4, 256, 0, stream>>>(za, zb, offs, col, dinv,
                                                 nullptr, nullptr, N);
    gather_acc_kernel<<<(B * 16 + 255) / 256, 256, 0, stream>>>(zb, drt, users, items,
                                                                baccU, baccI, B, nu);
    // layer 2 (full)
    pull_kernel<<<(N + 3) / 4, 256, 0, stream>>>(zb, za, offs, col, dinv,
                                                 nullptr, nullptr, N);
    gather_acc_kernel<<<(B * 16 + 255) / 256, 256, 0, stream>>>(za, drt, users, items,
                                                                baccU, baccI, B, nu);
    // layer 3 (sparse: only unique batch rows)
    pull_kernel<<<(2 * B + 3) / 4, 256, 0, stream>>>(za, zb, offs, col, dinv,
                                                     list, cnt, N);
    gather_acc_kernel<<<(B * 16 + 255) / 256, 256, 0, stream>>>(zb, drt, users, items,
                                                                baccU, baccI, B, nu);

    // epilogue: LDS-tiled GEMM + fused norm/dots
    proj_out_kernel<<<(B + 63) / 64, 256, 0, stream>>>(baccU, baccI, Tu, F, W, bv,
                                                       users, items, out, B, 0.25f);
}

// Round 3
// 907.425 us; speedup vs baseline: 1.7564x; 1.7564x over previous
//
#include <hip/hip_runtime.h>
#include <hip/hip_bf16.h>

// LightGCN forward on MI355X.
// R8: fixed sort-based build. R7's part_kernel (745us @ 0.37% VALU) died on
//     its own staging design: partial buckets never drained below BCAP, so
//     ~all 6M pairs fell through to a contended global atomicAdd on 587
//     counters (10k ops/counter, serialized). R8 replaces it with a standard
//     block-local counting sort: per block of 7168 edges -> LDS hist(587) ->
//     LDS scan -> ONE pcur reservation per (block,bucket) (0.25M atomics
//     total, ~420/counter) -> LDS reorder -> coalesced ~96B run writes.
//     Pairs packed to 1 int (dst_local<<18|src): 24MB not 48MB.
//     bhist parallelism 256->1024 blocks. build_kernel (bucket-local CSR
//     scatter, temporally clustered col writes) kept from R7.

#define WAVE 64
#define NBMAX 592   // max dst buckets; shift grows until NB <= NBMAX
#define SLOTS 14336 // pairs per scatter block (= 2 * 7168 edges)
#define ETG 1792    // int4 edge groups per scatter block (7168 edges)

typedef int nt_int4 __attribute__((ext_vector_type(4)));

// --- pass 1: per-bucket pair counts (edges read once) --------------------
__global__ __launch_bounds__(256) void bhist_kernel(const int* __restrict__ ue,
                                                    const int* __restrict__ ie,
                                                    int* __restrict__ bcnt,
                                                    int E, int nu, int NB, int shift,
                                                    int gpb, int NG) {
    __shared__ int lh[NBMAX];
    int tid = threadIdx.x;
    for (int b = tid; b < NB; b += 256) lh[b] = 0;
    __syncthreads();
    int g0 = blockIdx.x * gpb;
    int g1 = min(g0 + gpb, NG);
    for (int g = g0 + tid; g < g1; g += 256) {
        int e0 = g * 4;
        if (e0 + 3 < E) {
            nt_int4 u = __builtin_nontemporal_load((const nt_int4*)(ue + e0));
            nt_int4 v = __builtin_nontemporal_load((const nt_int4*)(ie + e0));
            atomicAdd(&lh[(nu + v.x) >> shift], 1); atomicAdd(&lh[u.x >> shift], 1);
            atomicAdd(&lh[(nu + v.y) >> shift], 1); atomicAdd(&lh[u.y >> shift], 1);
            atomicAdd(&lh[(nu + v.z) >> shift], 1); atomicAdd(&lh[u.z >> shift], 1);
            atomicAdd(&lh[(nu + v.w) >> shift], 1); atomicAdd(&lh[u.w >> shift], 1);
        } else {
            for (int e = e0; e < E; ++e) {
                atomicAdd(&lh[(nu + ie[e]) >> shift], 1);
                atomicAdd(&lh[ue[e] >> shift], 1);
            }
        }
    }
    __syncthreads();
    for (int b = tid; b < NB; b += 256) if (lh[b]) atomicAdd(&bcnt[b], lh[b]);
}

// --- pass 2: exclusive scan over NB bucket counts ------------------------
__global__ __launch_bounds__(1024) void bscan_kernel(const int* __restrict__ bcnt,
                                                     int* __restrict__ pbase,
                                                     int* __restrict__ pcur, int NB) {
    __shared__ int wsum[16];
    int t = threadIdx.x;
    int v0 = (t < NB) ? bcnt[t] : 0;
    int lane = t & 63, w = t >> 6;
    int v = v0;
    #pragma unroll
    for (int d = 1; d < 64; d <<= 1) {
        int o = __shfl_up(v, d, 64);
        if (lane >= d) v += o;
    }
    if (lane == 63) wsum[w] = v;
    __syncthreads();
    if (t == 0) {
        int r = 0;
        #pragma unroll
        for (int k = 0; k < 16; ++k) { int s = wsum[k]; wsum[k] = r; r += s; }
    }
    __syncthreads();
    int excl = (v - v0) + wsum[w];
    if (t < NB) { pbase[t] = excl; pcur[t] = excl; }
}

// --- pass 3: block-local counting-sort partition -------------------------
// Per block: hist -> scan -> one pcur reservation per bucket -> LDS reorder
// -> coalesced run writes (avg run ~24 pairs = 96B). No per-pair global
// atomics; packed pair = (dst_local << 18) | src  (src < 2^18, dl < 2^9).
__global__ __launch_bounds__(256) void scatter_kernel(const int* __restrict__ ue,
                                                      const int* __restrict__ ie,
                                                      int* __restrict__ pcur,
                                                      int* __restrict__ pairs,
                                                      int E, int nu, int shift,
                                                      int NB, int NG) {
    __shared__ int slot[SLOTS];
    __shared__ int lhist[NBMAX];
    __shared__ int lcur[NBMAX];
    __shared__ int gbase[NBMAX];
    int tid = threadIdx.x;
    for (int b = tid; b < NB; b += 256) lhist[b] = 0;
    __syncthreads();
    int g0 = blockIdx.x * ETG;
    int g1 = min(g0 + ETG, NG);
    int mask = (1 << shift) - 1;
    // pass A: count
    for (int g = g0 + tid; g < g1; g += 256) {
        int e0 = g * 4;
        if (e0 + 3 < E) {
            nt_int4 u = __builtin_nontemporal_load((const nt_int4*)(ue + e0));
            nt_int4 v = __builtin_nontemporal_load((const nt_int4*)(ie + e0));
            atomicAdd(&lhist[(nu + v.x) >> shift], 1); atomicAdd(&lhist[u.x >> shift], 1);
            atomicAdd(&lhist[(nu + v.y) >> shift], 1); atomicAdd(&lhist[u.y >> shift], 1);
            atomicAdd(&lhist[(nu + v.z) >> shift], 1); atomicAdd(&lhist[u.z >> shift], 1);
            atomicAdd(&lhist[(nu + v.w) >> shift], 1); atomicAdd(&lhist[u.w >> shift], 1);
        } else {
            for (int e = e0; e < E; ++e) {
                atomicAdd(&lhist[(nu + ie[e]) >> shift], 1);
                atomicAdd(&lhist[ue[e] >> shift], 1);
            }
        }
    }
    __syncthreads();
    // exclusive scan of lhist -> lcur (wave 0, chunks of 64 with carry)
    if (tid < 64) {
        int carry = 0;
        for (int c = 0; c < NB; c += 64) {
            int idx = c + tid;
            int x = (idx < NB) ? lhist[idx] : 0;
            int v = x;
            #pragma unroll
            for (int d = 1; d < 64; d <<= 1) {
                int o = __shfl_up(v, d, 64);
                if (tid >= d) v += o;
            }
            if (idx < NB) lcur[idx] = v - x + carry;
            carry += __shfl(v, 63, 64);
        }
    }
    __syncthreads();
    // one global reservation per non-empty bucket
    for (int b = tid; b < NB; b += 256) {
        int c = lhist[b];
        if (c) gbase[b] = atomicAdd(&pcur[b], c);
    }
    // pass B: place into bucket-contiguous LDS slots (lcur is the cursor)
    for (int g = g0 + tid; g < g1; g += 256) {
        int e0 = g * 4;
        if (e0 + 3 < E) {
            nt_int4 u = __builtin_nontemporal_load((const nt_int4*)(ue + e0));
            nt_int4 v = __builtin_nontemporal_load((const nt_int4*)(ie + e0));
            int uu[4] = {u.x, u.y, u.z, u.w};
            int vv[4] = {nu + v.x, nu + v.y, nu + v.z, nu + v.w};
            #pragma unroll
            for (int t = 0; t < 4; ++t) {
                int d = vv[t], s = uu[t];
                int p = atomicAdd(&lcur[d >> shift], 1);
                slot[p] = ((d & mask) << 18) | s;
                d = uu[t]; s = vv[t];
                p = atomicAdd(&lcur[d >> shift], 1);
                slot[p] = ((d & mask) << 18) | s;
            }
        } else {
            for (int e = e0; e < E; ++e) {
                int d = nu + ie[e], s = ue[e];
                int p = atomicAdd(&lcur[d >> shift], 1);
                slot[p] = ((d & mask) << 18) | s;
                d = ue[e]; s = nu + ie[e];
                p = atomicAdd(&lcur[d >> shift], 1);
                slot[p] = ((d & mask) << 18) | s;
            }
        }
    }
    __syncthreads();
    // write out runs: one wave per bucket, strided; coalesced within run
    int w = tid >> 6, lane = tid & 63;
    for (int b = w; b < NB; b += 4) {
        int c = lhist[b];
        if (!c) continue;
        int start = lcur[b] - c;   // cursor ended at start + c
        int gb = gbase[b];
        for (int i = lane; i < c; i += 64)
            pairs[gb + i] = slot[start + i];
    }
}

// --- pass 4: per-bucket CSR build (deg hist + local scan + scatter) ------
// One block per bucket; all col writes for the bucket's ~41KB window happen
// within one block lifetime -> each line written back once.
__global__ __launch_bounds__(256) void build_kernel(const int* __restrict__ pairs,
                                                    const int* __restrict__ pbase,
                                                    const int* __restrict__ pcur,
                                                    int* __restrict__ offs,
                                                    float* __restrict__ dinv,
                                                    float* __restrict__ drt,
                                                    int* __restrict__ col,
                                                    int N, int shift, int NB, int twoE) {
    __shared__ int dcnt[512];
    __shared__ int ex[512];
    __shared__ int cur[512];
    int b = blockIdx.x, tid = threadIdx.x;
    int lo = b << shift;
    int n = min(1 << shift, N - lo);
    for (int i = tid; i < 512; i += 256) dcnt[i] = 0;
    __syncthreads();
    int pb = pbase[b];
    int cnt = pcur[b] - pb;
    for (int i = tid; i < cnt; i += 256) {
        int p = pairs[pb + i];
        atomicAdd(&dcnt[p >> 18], 1);
    }
    __syncthreads();
    // exclusive scan of dcnt[0..512) by wave 0 (8 serial per lane + wave scan)
    if (tid < 64) {
        int base = tid * 8;
        int loc[8]; int s = 0;
        #pragma unroll
        for (int k = 0; k < 8; ++k) { loc[k] = s; s += dcnt[base + k]; }
        int v = s;
        #pragma unroll
        for (int d = 1; d < 64; d <<= 1) {
            int o = __shfl_up(v, d, 64);
            if (tid >= d) v += o;
        }
        int excl = v - s;
        #pragma unroll
        for (int k = 0; k < 8; ++k) ex[base + k] = excl + loc[k];
    }
    __syncthreads();
    for (int i = tid; i < n; i += 256) {
        int c = pb + ex[i];
        cur[i] = c;
        offs[lo + i] = c;
        int d = dcnt[i];
        dinv[lo + i] = (d > 0) ? rsqrtf((float)d) : 0.0f;
        drt[lo + i]  = (d > 0) ? sqrtf((float)d)  : 0.0f;
    }
    if (b == NB - 1 && tid == 0) offs[N] = twoE;
    __syncthreads();
    for (int i = tid; i < cnt; i += 256) {
        int p = pairs[pb + i];
        int pos = atomicAdd(&cur[p >> 18], 1);
        col[pos] = p & 0x3FFFF;
    }
}

// --- batch-node marking / compaction -------------------------------------
__global__ void mark_kernel(const int* __restrict__ users, const int* __restrict__ items,
                            int* __restrict__ flag, int B, int nu) {
    int b = blockIdx.x * blockDim.x + threadIdx.x;
    if (b < B) {
        flag[users[b]] = 1;
        flag[nu + items[b]] = 1;
    }
}

__global__ void compact_kernel(const int* __restrict__ flag, int* __restrict__ list,
                               int* __restrict__ cnt, int N) {
    int n = blockIdx.x * blockDim.x + threadIdx.x;
    if (n < N && flag[n]) {
        int pos = atomicAdd(cnt, 1);
        list[pos] = n;
    }
}

__global__ void init_z_kernel(const float* __restrict__ Gu, const float* __restrict__ Gi,
                              const float* __restrict__ dinv,
                              float* __restrict__ z, int nuQ, int totQ) {
    int i = blockIdx.x * blockDim.x + threadIdx.x;  // float4 slots
    if (i < totQ) {
        const float4* src = (i < nuQ) ? (const float4*)Gu : (const float4*)Gi;
        int j = (i < nuQ) ? i : i - nuQ;
        float4 a = src[j];
        float w = dinv[i >> 4];
        a.x *= w; a.y *= w; a.z *= w; a.w *= w;
        ((float4*)z)[i] = a;
    }
}

__global__ void init_bacc_kernel(const float* __restrict__ Gu, const float* __restrict__ Gi,
                                 const int* __restrict__ users, const int* __restrict__ items,
                                 float* __restrict__ baccU, float* __restrict__ baccI, int B) {
    int id = blockIdx.x * blockDim.x + threadIdx.x;  // B*16 float4 slots
    if (id < B * 16) {
        int b = id >> 4, q = id & 15;
        ((float4*)baccU)[id] = ((const float4*)Gu)[(size_t)users[b] * 16 + q];
        ((float4*)baccI)[id] = ((const float4*)Gi)[(size_t)items[b] * 16 + q];
    }
}

// One wave per destination row. z_next[r] = dinv[r]^2 * sum_{c in N(r)} z[c].
__global__ __launch_bounds__(256) void pull_kernel(const float* __restrict__ z,
                                                   float* __restrict__ zn,
                                                   const int* __restrict__ offs,
                                                   const int* __restrict__ col,
                                                   const float* __restrict__ dinv,
                                                   const int* __restrict__ rows,
                                                   const int* __restrict__ n_ptr, int N) {
    int wid = (blockIdx.x * blockDim.x + threadIdx.x) >> 6;
    int lane = threadIdx.x & 63;
    int nrows = rows ? *n_ptr : N;
    if (wid >= nrows) return;
    int r = rows ? rows[wid] : wid;
    int s = offs[r], e = offs[r + 1];
    float acc0 = 0.0f, acc1 = 0.0f;
    for (int base = s; base < e; base += 64) {
        int idx = base + lane;
        int c = (idx < e) ? __builtin_nontemporal_load(col + idx) : 0;
        int n = min(64, e - base);
        int j = 0;
        for (; j + 4 <= n; j += 4) {
            int c0 = __shfl(c, j),     c1 = __shfl(c, j + 1);
            int c2 = __shfl(c, j + 2), c3 = __shfl(c, j + 3);
            float v0 = z[(size_t)c0 * WAVE + lane];
            float v1 = z[(size_t)c1 * WAVE + lane];
            float v2 = z[(size_t)c2 * WAVE + lane];
            float v3 = z[(size_t)c3 * WAVE + lane];
            acc0 += v0 + v1;
            acc1 += v2 + v3;
        }
        for (; j < n; ++j) {
            int cj = __shfl(c, j);
            acc0 += z[(size_t)cj * WAVE + lane];
        }
    }
    float w = dinv[r];
    zn[(size_t)r * WAVE + lane] = w * w * (acc0 + acc1);
}

__global__ void gather_acc_kernel(const float* __restrict__ zn,
                                  const float* __restrict__ drt,
                                  const int* __restrict__ users, const int* __restrict__ items,
                                  float* __restrict__ baccU, float* __restrict__ baccI,
                                  int B, int nu) {
    int id = blockIdx.x * blockDim.x + threadIdx.x;  // B*16 float4 slots
    if (id < B * 16) {
        int b = id >> 4, q = id & 15;
        int u = users[b], it = nu + items[b];
        float wu = drt[u], wi = drt[it];
        float4 a = ((float4*)baccU)[id];
        float4 v = ((const float4*)zn)[(size_t)u * 16 + q];
        a.x += wu * v.x; a.y += wu * v.y; a.z += wu * v.z; a.w += wu * v.w;
        ((float4*)baccU)[id] = a;
        float4 c = ((float4*)baccI)[id];
        float4 d = ((const float4*)zn)[(size_t)it * 16 + q];
        c.x += wi * d.x; c.y += wi * d.y; c.z += wi * d.z; c.w += wi * d.w;
        ((float4*)baccI)[id] = c;
    }
}

// LDS-tiled fp32 GEMM + fused epilogue.
// Block: 64 batch-rows x 64 outputs, 256 threads, 4x4 reg tile/thread.
__global__ __launch_bounds__(256) void proj_out_kernel(const float* __restrict__ baccU,
                                                       const float* __restrict__ baccI,
                                                       const float* __restrict__ Tu,
                                                       const float* __restrict__ F,
                                                       const float* __restrict__ W,
                                                       const float* __restrict__ bvec,
                                                       const int* __restrict__ users,
                                                       const int* __restrict__ items,
                                                       float* __restrict__ out,
                                                       int B, float invL) {
    const int FEATn = 1024;
    __shared__ float Ft[2][32][64];
    __shared__ float Wt[2][32][64];

    int tid = threadIdx.x;
    int tx = tid & 15;        // col group (4 cols)
    int ty = tid >> 4;        // row group (4 rows)
    int r0 = blockIdx.x * 64;

    int lr = tid >> 2;                       // 0..63
    int lq = tid & 3;                        // quad group: local kk 4*lq and 4*lq+16
    int frow = min(r0 + lr, B - 1);
    const float* Fp = F + (size_t)items[frow] * FEATn + lq * 4;
    const float* Wp = W + (size_t)lr * FEATn + lq * 4;

    float4 fa0 = *(const float4*)(Fp);
    float4 fa1 = *(const float4*)(Fp + 16);
    float4 wa0 = *(const float4*)(Wp);
    float4 wa1 = *(const float4*)(Wp + 16);

    float acc[4][4] = {};

    for (int kt = 0; kt < 32; ++kt) {
        int buf = kt & 1;
        #pragma unroll
        for (int i = 0; i < 4; ++i) {
            Ft[buf][lq * 4 + i][lr]      = ((const float*)&fa0)[i];
            Ft[buf][lq * 4 + 16 + i][lr] = ((const float*)&fa1)[i];
            Wt[buf][lq * 4 + i][lr]      = ((const float*)&wa0)[i];
            Wt[buf][lq * 4 + 16 + i][lr] = ((const float*)&wa1)[i];
        }
        __syncthreads();
        if (kt < 31) {
            const float* fp = Fp + (kt + 1) * 32;
            const float* wp = Wp + (kt + 1) * 32;
            fa0 = *(const float4*)(fp);
            fa1 = *(const float4*)(fp + 16);
            wa0 = *(const float4*)(wp);
            wa1 = *(const float4*)(wp + 16);
        }
        #pragma unroll 8
        for (int kk = 0; kk < 32; ++kk) {
            float4 a = *(const float4*)&Ft[buf][kk][ty * 4];
            float4 b = *(const float4*)&Wt[buf][kk][tx * 4];
            acc[0][0] = fmaf(a.x, b.x, acc[0][0]);
            acc[0][1] = fmaf(a.x, b.y, acc[0][1]);
            acc[0][2] = fmaf(a.x, b.z, acc[0][2]);
            acc[0][3] = fmaf(a.x, b.w, acc[0][3]);
            acc[1][0] = fmaf(a.y, b.x, acc[1][0]);
            acc[1][1] = fmaf(a.y, b.y, acc[1][1]);
            acc[1][2] = fmaf(a.y, b.z, acc[1][2]);
            acc[1][3] = fmaf(a.y, b.w, acc[1][3]);
            acc[2][0] = fmaf(a.z, b.x, acc[2][0]);
            acc[2][1] = fmaf(a.z, b.y, acc[2][1]);
            acc[2][2] = fmaf(a.z, b.z, acc[2][2]);
            acc[2][3] = fmaf(a.z, b.w, acc[2][3]);
            acc[3][0] = fmaf(a.w, b.x, acc[3][0]);
            acc[3][1] = fmaf(a.w, b.y, acc[3][1]);
            acc[3][2] = fmaf(a.w, b.z, acc[3][2]);
            acc[3][3] = fmaf(a.w, b.w, acc[3][3]);
        }
    }

    float4 bb = *(const float4*)(bvec + tx * 4);
    float L2 = invL * invL;
    float res[4];
    #pragma unroll
    for (int r = 0; r < 4; ++r) {
        int gr = min(r0 + ty * 4 + r, B - 1);
        float pb0 = acc[r][0] + bb.x;
        float pb1 = acc[r][1] + bb.y;
        float pb2 = acc[r][2] + bb.z;
        float pb3 = acc[r][3] + bb.w;
        float s = pb0 * pb0 + pb1 * pb1 + pb2 * pb2 + pb3 * pb3;
        #pragma unroll
        for (int d = 1; d < 16; d <<= 1) s += __shfl_xor(s, d, 64);
        float inv = 1.0f / fmaxf(sqrtf(s), 1e-12f);
        int u = users[gr];
        float4 tu = *(const float4*)(Tu + (size_t)u * WAVE + tx * 4);
        float4 gu = *(const float4*)(baccU + (size_t)gr * WAVE + tx * 4);
        float4 gi = *(const float4*)(baccI + (size_t)gr * WAVE + tx * 4);
        float dsum = L2 * (gu.x * gi.x + gu.y * gi.y + gu.z * gi.z + gu.w * gi.w)
                   + inv * (tu.x * pb0 + tu.y * pb1 + tu.z * pb2 + tu.w * pb3);
        #pragma unroll
        for (int d = 1; d < 16; d <<= 1) dsum += __shfl_xor(dsum, d, 64);
        res[r] = dsum;
    }
    if (tx == 0) {
        #pragma unroll
        for (int r = 0; r < 4; ++r) {
            int gr = r0 + ty * 4 + r;
            if (gr < B) out[gr] = res[r];
        }
    }
}

extern "C" void kernel_launch(void* const* d_in, const int* in_sizes, int n_in,
                              void* d_out, int out_size, void* d_ws, size_t ws_size,
                              hipStream_t stream) {
    const float* Gu = (const float*)d_in[0];
    const float* Gi = (const float*)d_in[1];
    const float* Tu = (const float*)d_in[2];
    const float* F  = (const float*)d_in[3];
    const float* W  = (const float*)d_in[4];
    const float* bv = (const float*)d_in[5];
    const int* ue    = (const int*)d_in[6];
    const int* ie    = (const int*)d_in[7];
    const int* users = (const int*)d_in[8];
    const int* items = (const int*)d_in[9];
    float* out = (float*)d_out;

    const int K  = 64;
    const int nu = in_sizes[0] / K;
    const int ni = in_sizes[1] / K;
    const int N  = nu + ni;
    const int E  = in_sizes[6];
    const int B  = in_sizes[8];

    char* p = (char*)d_ws;
    auto alloc = [&](size_t bytes) -> void* {
        void* r = (void*)p;
        p += (bytes + 255) & ~(size_t)255;
        return r;
    };
    float* dinv   = (float*)alloc((size_t)N * 4);
    float* drt    = (float*)alloc((size_t)N * 4);
    int*   offs   = (int*)  alloc((size_t)(N + 1) * 4);
    int*   flags  = (int*)  alloc((size_t)N * 4);
    int*   col    = (int*)  alloc((size_t)2 * E * 4);
    float* za     = (float*)alloc((size_t)N * K * 4);
    float* zb     = (float*)alloc((size_t)N * K * 4);
    float* baccU  = (float*)alloc((size_t)B * K * 4);
    float* baccI  = (float*)alloc((size_t)B * K * 4);
    int*   list   = (int*)  alloc((size_t)2 * B * 4);
    int*   cnt    = (int*)  alloc(256);
    int*   bcnt   = (int*)  alloc((size_t)NBMAX * 4);
    int*   pbase  = (int*)  alloc((size_t)NBMAX * 4);
    int*   pcur   = (int*)  alloc((size_t)NBMAX * 4);

    // bucket geometry: 256 nodes/bucket (shift 8) for this problem size
    int shift = 8;
    while (((N + (1 << shift) - 1) >> shift) > NBMAX) ++shift;
    const int NB = (N + (1 << shift) - 1) >> shift;

    // packed pair staging (2E ints = 24MB) aliases za (38.4MB): pairs are
    // dead before init_z writes za.
    int* pairs = (int*)za;

    const int NG   = (E + 3) / 4;            // int4 edge groups
    const int gpbH = (NG + 1023) / 1024;     // groups per bhist block
    const int nbS  = (NG + ETG - 1) / ETG;   // scatter blocks

    // graph build
    hipMemsetAsync(bcnt, 0, (size_t)NB * 4, stream);
    bhist_kernel<<<1024, 256, 0, stream>>>(ue, ie, bcnt, E, nu, NB, shift, gpbH, NG);
    bscan_kernel<<<1, 1024, 0, stream>>>(bcnt, pbase, pcur, NB);
    scatter_kernel<<<nbS, 256, 0, stream>>>(ue, ie, pcur, pairs, E, nu, shift, NB, NG);
    build_kernel<<<NB, 256, 0, stream>>>(pairs, pbase, pcur, offs, dinv, drt, col,
                                         N, shift, NB, 2 * E);

    // batch-node list
    hipMemsetAsync(flags, 0, (size_t)N * 4, stream);
    hipMemsetAsync(cnt, 0, 4, stream);
    mark_kernel<<<(B + 255) / 256, 256, 0, stream>>>(users, items, flags, B, nu);
    compact_kernel<<<(N + 255) / 256, 256, 0, stream>>>(flags, list, cnt, N);

    // init
    int totQ = N * K / 4, nuQ = nu * K / 4;
    init_z_kernel<<<(totQ + 255) / 256, 256, 0, stream>>>(Gu, Gi, dinv, za, nuQ, totQ);
    init_bacc_kernel<<<(B * 16 + 255) / 256, 256, 0, stream>>>(Gu, Gi, users, items,
                                                               baccU, baccI, B);

    // layer 1 (full)
    pull_kernel<<<(N + 3) / 4, 256, 0, stream>>>(za, zb, offs, col, dinv,
                                                 nullptr, nullptr, N);
    gather_acc_kernel<<<(B * 16 + 255) / 256, 256, 0, stream>>>(zb, drt, users, items,
                                                                baccU, baccI, B, nu);
    // layer 2 (full)
    pull_kernel<<<(N + 3) / 4, 256, 0, stream>>>(zb, za, offs, col, dinv,
                                                 nullptr, nullptr, N);
    gather_acc_kernel<<<(B * 16 + 255) / 256, 256, 0, stream>>>(za, drt, users, items,
                                                                baccU, baccI, B, nu);
    // layer 3 (sparse: only unique batch rows)
    pull_kernel<<<(2 * B + 3) / 4, 256, 0, stream>>>(za, zb, offs, col, dinv,
                                                     list, cnt, N);
    gather_acc_kernel<<<(B * 16 + 255) / 256, 256, 0, stream>>>(zb, drt, users, items,
                                                                baccU, baccI, B, nu);

    // epilogue: LDS-tiled GEMM + fused norm/dots
    proj_out_kernel<<<(B + 63) / 64, 256, 0, stream>>>(baccU, baccI, Tu, F, W, bv,
                                                       users, items, out, B, 0.25f);
}

// Round 4
// 775.511 us; speedup vs baseline: 2.0551x; 1.1701x over previous
//
#include <hip/hip_runtime.h>
#include <hip/hip_bf16.h>
#include <hip/hip_fp16.h>

// LightGCN forward on MI355X.
// R9: fp16 z-storage for the propagation layers. R8 got the sort-based build
//     working (1594->907us); pull_kernel now dominates (2x178us + sparse) at
//     FETCH=598MB, 3.6TB/s, VALU 30%. Little's law says pull is traffic-bound
//     (not latency): 1.54GB logical gather, L2 captures only 2.6x (random
//     neighbors over a 38.4MB z vs 4MB/XCD L2). Only levers: fewer bytes or
//     more reuse; source-blocking is capped by 8-XCD topology. So: store
//     z/zn as fp16 (math in fp32) -> rows 128B, logical traffic halved, and
//     z=19.2MB doubles the L2-cached fraction. Only the gamma_u.gamma_i term
//     is affected (theta.proj path is pure fp32); predicted absmax ~1e-4.
//     Graph build (bhist/bscan/scatter/build) unchanged from R8.

#define WAVE 64
#define NBMAX 592   // max dst buckets; shift grows until NB <= NBMAX
#define SLOTS 14336 // pairs per scatter block (= 2 * 7168 edges)
#define ETG 1792    // int4 edge groups per scatter block (7168 edges)

typedef int nt_int4 __attribute__((ext_vector_type(4)));

__device__ __forceinline__ unsigned pack2(float lo, float hi) {
    __half2 h = __floats2half2_rn(lo, hi);
    return *(unsigned*)&h;
}
__device__ __forceinline__ float2 unpack2(unsigned u) {
    __half2 h = *(__half2*)&u;
    return __half22float2(h);
}

// --- pass 1: per-bucket pair counts (edges read once) --------------------
__global__ __launch_bounds__(256) void bhist_kernel(const int* __restrict__ ue,
                                                    const int* __restrict__ ie,
                                                    int* __restrict__ bcnt,
                                                    int E, int nu, int NB, int shift,
                                                    int gpb, int NG) {
    __shared__ int lh[NBMAX];
    int tid = threadIdx.x;
    for (int b = tid; b < NB; b += 256) lh[b] = 0;
    __syncthreads();
    int g0 = blockIdx.x * gpb;
    int g1 = min(g0 + gpb, NG);
    for (int g = g0 + tid; g < g1; g += 256) {
        int e0 = g * 4;
        if (e0 + 3 < E) {
            nt_int4 u = __builtin_nontemporal_load((const nt_int4*)(ue + e0));
            nt_int4 v = __builtin_nontemporal_load((const nt_int4*)(ie + e0));
            atomicAdd(&lh[(nu + v.x) >> shift], 1); atomicAdd(&lh[u.x >> shift], 1);
            atomicAdd(&lh[(nu + v.y) >> shift], 1); atomicAdd(&lh[u.y >> shift], 1);
            atomicAdd(&lh[(nu + v.z) >> shift], 1); atomicAdd(&lh[u.z >> shift], 1);
            atomicAdd(&lh[(nu + v.w) >> shift], 1); atomicAdd(&lh[u.w >> shift], 1);
        } else {
            for (int e = e0; e < E; ++e) {
                atomicAdd(&lh[(nu + ie[e]) >> shift], 1);
                atomicAdd(&lh[ue[e] >> shift], 1);
            }
        }
    }
    __syncthreads();
    for (int b = tid; b < NB; b += 256) if (lh[b]) atomicAdd(&bcnt[b], lh[b]);
}

// --- pass 2: exclusive scan over NB bucket counts ------------------------
__global__ __launch_bounds__(1024) void bscan_kernel(const int* __restrict__ bcnt,
                                                     int* __restrict__ pbase,
                                                     int* __restrict__ pcur, int NB) {
    __shared__ int wsum[16];
    int t = threadIdx.x;
    int v0 = (t < NB) ? bcnt[t] : 0;
    int lane = t & 63, w = t >> 6;
    int v = v0;
    #pragma unroll
    for (int d = 1; d < 64; d <<= 1) {
        int o = __shfl_up(v, d, 64);
        if (lane >= d) v += o;
    }
    if (lane == 63) wsum[w] = v;
    __syncthreads();
    if (t == 0) {
        int r = 0;
        #pragma unroll
        for (int k = 0; k < 16; ++k) { int s = wsum[k]; wsum[k] = r; r += s; }
    }
    __syncthreads();
    int excl = (v - v0) + wsum[w];
    if (t < NB) { pbase[t] = excl; pcur[t] = excl; }
}

// --- pass 3: block-local counting-sort partition -------------------------
__global__ __launch_bounds__(256) void scatter_kernel(const int* __restrict__ ue,
                                                      const int* __restrict__ ie,
                                                      int* __restrict__ pcur,
                                                      int* __restrict__ pairs,
                                                      int E, int nu, int shift,
                                                      int NB, int NG) {
    __shared__ int slot[SLOTS];
    __shared__ int lhist[NBMAX];
    __shared__ int lcur[NBMAX];
    __shared__ int gbase[NBMAX];
    int tid = threadIdx.x;
    for (int b = tid; b < NB; b += 256) lhist[b] = 0;
    __syncthreads();
    int g0 = blockIdx.x * ETG;
    int g1 = min(g0 + ETG, NG);
    int mask = (1 << shift) - 1;
    // pass A: count
    for (int g = g0 + tid; g < g1; g += 256) {
        int e0 = g * 4;
        if (e0 + 3 < E) {
            nt_int4 u = __builtin_nontemporal_load((const nt_int4*)(ue + e0));
            nt_int4 v = __builtin_nontemporal_load((const nt_int4*)(ie + e0));
            atomicAdd(&lhist[(nu + v.x) >> shift], 1); atomicAdd(&lhist[u.x >> shift], 1);
            atomicAdd(&lhist[(nu + v.y) >> shift], 1); atomicAdd(&lhist[u.y >> shift], 1);
            atomicAdd(&lhist[(nu + v.z) >> shift], 1); atomicAdd(&lhist[u.z >> shift], 1);
            atomicAdd(&lhist[(nu + v.w) >> shift], 1); atomicAdd(&lhist[u.w >> shift], 1);
        } else {
            for (int e = e0; e < E; ++e) {
                atomicAdd(&lhist[(nu + ie[e]) >> shift], 1);
                atomicAdd(&lhist[ue[e] >> shift], 1);
            }
        }
    }
    __syncthreads();
    // exclusive scan of lhist -> lcur (wave 0, chunks of 64 with carry)
    if (tid < 64) {
        int carry = 0;
        for (int c = 0; c < NB; c += 64) {
            int idx = c + tid;
            int x = (idx < NB) ? lhist[idx] : 0;
            int v = x;
            #pragma unroll
            for (int d = 1; d < 64; d <<= 1) {
                int o = __shfl_up(v, d, 64);
                if (tid >= d) v += o;
            }
            if (idx < NB) lcur[idx] = v - x + carry;
            carry += __shfl(v, 63, 64);
        }
    }
    __syncthreads();
    // one global reservation per non-empty bucket
    for (int b = tid; b < NB; b += 256) {
        int c = lhist[b];
        if (c) gbase[b] = atomicAdd(&pcur[b], c);
    }
    // pass B: place into bucket-contiguous LDS slots
    for (int g = g0 + tid; g < g1; g += 256) {
        int e0 = g * 4;
        if (e0 + 3 < E) {
            nt_int4 u = __builtin_nontemporal_load((const nt_int4*)(ue + e0));
            nt_int4 v = __builtin_nontemporal_load((const nt_int4*)(ie + e0));
            int uu[4] = {u.x, u.y, u.z, u.w};
            int vv[4] = {nu + v.x, nu + v.y, nu + v.z, nu + v.w};
            #pragma unroll
            for (int t = 0; t < 4; ++t) {
                int d = vv[t], s = uu[t];
                int p = atomicAdd(&lcur[d >> shift], 1);
                slot[p] = ((d & mask) << 18) | s;
                d = uu[t]; s = vv[t];
                p = atomicAdd(&lcur[d >> shift], 1);
                slot[p] = ((d & mask) << 18) | s;
            }
        } else {
            for (int e = e0; e < E; ++e) {
                int d = nu + ie[e], s = ue[e];
                int p = atomicAdd(&lcur[d >> shift], 1);
                slot[p] = ((d & mask) << 18) | s;
                d = ue[e]; s = nu + ie[e];
                p = atomicAdd(&lcur[d >> shift], 1);
                slot[p] = ((d & mask) << 18) | s;
            }
        }
    }
    __syncthreads();
    // write out runs: one wave per bucket, strided; coalesced within run
    int w = tid >> 6, lane = tid & 63;
    for (int b = w; b < NB; b += 4) {
        int c = lhist[b];
        if (!c) continue;
        int start = lcur[b] - c;   // cursor ended at start + c
        int gb = gbase[b];
        for (int i = lane; i < c; i += 64)
            pairs[gb + i] = slot[start + i];
    }
}

// --- pass 4: per-bucket CSR build (deg hist + local scan + scatter) ------
__global__ __launch_bounds__(256) void build_kernel(const int* __restrict__ pairs,
                                                    const int* __restrict__ pbase,
                                                    const int* __restrict__ pcur,
                                                    int* __restrict__ offs,
                                                    float* __restrict__ dinv,
                                                    float* __restrict__ drt,
                                                    int* __restrict__ col,
                                                    int N, int shift, int NB, int twoE) {
    __shared__ int dcnt[512];
    __shared__ int ex[512];
    __shared__ int cur[512];
    int b = blockIdx.x, tid = threadIdx.x;
    int lo = b << shift;
    int n = min(1 << shift, N - lo);
    for (int i = tid; i < 512; i += 256) dcnt[i] = 0;
    __syncthreads();
    int pb = pbase[b];
    int cnt = pcur[b] - pb;
    for (int i = tid; i < cnt; i += 256) {
        int p = pairs[pb + i];
        atomicAdd(&dcnt[p >> 18], 1);
    }
    __syncthreads();
    if (tid < 64) {
        int base = tid * 8;
        int loc[8]; int s = 0;
        #pragma unroll
        for (int k = 0; k < 8; ++k) { loc[k] = s; s += dcnt[base + k]; }
        int v = s;
        #pragma unroll
        for (int d = 1; d < 64; d <<= 1) {
            int o = __shfl_up(v, d, 64);
            if (tid >= d) v += o;
        }
        int excl = v - s;
        #pragma unroll
        for (int k = 0; k < 8; ++k) ex[base + k] = excl + loc[k];
    }
    __syncthreads();
    for (int i = tid; i < n; i += 256) {
        int c = pb + ex[i];
        cur[i] = c;
        offs[lo + i] = c;
        int d = dcnt[i];
        dinv[lo + i] = (d > 0) ? rsqrtf((float)d) : 0.0f;
        drt[lo + i]  = (d > 0) ? sqrtf((float)d)  : 0.0f;
    }
    if (b == NB - 1 && tid == 0) offs[N] = twoE;
    __syncthreads();
    for (int i = tid; i < cnt; i += 256) {
        int p = pairs[pb + i];
        int pos = atomicAdd(&cur[p >> 18], 1);
        col[pos] = p & 0x3FFFF;
    }
}

// --- batch-node marking / compaction -------------------------------------
__global__ void mark_kernel(const int* __restrict__ users, const int* __restrict__ items,
                            int* __restrict__ flag, int B, int nu) {
    int b = blockIdx.x * blockDim.x + threadIdx.x;
    if (b < B) {
        flag[users[b]] = 1;
        flag[nu + items[b]] = 1;
    }
}

__global__ void compact_kernel(const int* __restrict__ flag, int* __restrict__ list,
                               int* __restrict__ cnt, int N) {
    int n = blockIdx.x * blockDim.x + threadIdx.x;
    if (n < N && flag[n]) {
        int pos = atomicAdd(cnt, 1);
        list[pos] = n;
    }
}

// z init: za[n][k] = dinv[n] * x0[n][k], stored fp16. One thread = 8 k-dims
// (16B store). id over N*8.
__global__ void init_z_kernel(const float* __restrict__ Gu, const float* __restrict__ Gi,
                              const float* __restrict__ dinv,
                              __half* __restrict__ z, int nu, int N) {
    int id = blockIdx.x * blockDim.x + threadIdx.x;
    if (id < N * 8) {
        int n = id >> 3, q = id & 7;
        const float4* src = (n < nu) ? (const float4*)Gu : (const float4*)Gi;
        int j = (n < nu) ? n : n - nu;
        float4 a0 = src[(size_t)j * 16 + q * 2];
        float4 a1 = src[(size_t)j * 16 + q * 2 + 1];
        float w = dinv[n];
        uint4 o;
        o.x = pack2(a0.x * w, a0.y * w);
        o.y = pack2(a0.z * w, a0.w * w);
        o.z = pack2(a1.x * w, a1.y * w);
        o.w = pack2(a1.z * w, a1.w * w);
        ((uint4*)z)[id] = o;
    }
}

__global__ void init_bacc_kernel(const float* __restrict__ Gu, const float* __restrict__ Gi,
                                 const int* __restrict__ users, const int* __restrict__ items,
                                 float* __restrict__ baccU, float* __restrict__ baccI, int B) {
    int id = blockIdx.x * blockDim.x + threadIdx.x;  // B*16 float4 slots
    if (id < B * 16) {
        int b = id >> 4, q = id & 15;
        ((float4*)baccU)[id] = ((const float4*)Gu)[(size_t)users[b] * 16 + q];
        ((float4*)baccI)[id] = ((const float4*)Gi)[(size_t)items[b] * 16 + q];
    }
}

// One wave per destination row. zn[r] = fp16(dinv[r]^2 * sum_{c in N(r)} z[c]).
// fp16 rows = 128B, fully coalesced (ushort/lane); math fp32.
__global__ __launch_bounds__(256) void pull_kernel(const __half* __restrict__ z,
                                                   __half* __restrict__ zn,
                                                   const int* __restrict__ offs,
                                                   const int* __restrict__ col,
                                                   const float* __restrict__ dinv,
                                                   const int* __restrict__ rows,
                                                   const int* __restrict__ n_ptr, int N) {
    int wid = (blockIdx.x * blockDim.x + threadIdx.x) >> 6;
    int lane = threadIdx.x & 63;
    int nrows = rows ? *n_ptr : N;
    if (wid >= nrows) return;
    int r = rows ? rows[wid] : wid;
    int s = offs[r], e = offs[r + 1];
    float acc0 = 0.0f, acc1 = 0.0f, acc2 = 0.0f, acc3 = 0.0f;
    for (int base = s; base < e; base += 64) {
        int idx = base + lane;
        int c = (idx < e) ? __builtin_nontemporal_load(col + idx) : 0;
        int n = min(64, e - base);
        int j = 0;
        for (; j + 8 <= n; j += 8) {
            int c0 = __shfl(c, j),     c1 = __shfl(c, j + 1);
            int c2 = __shfl(c, j + 2), c3 = __shfl(c, j + 3);
            int c4 = __shfl(c, j + 4), c5 = __shfl(c, j + 5);
            int c6 = __shfl(c, j + 6), c7 = __shfl(c, j + 7);
            float v0 = __half2float(z[(size_t)c0 * WAVE + lane]);
            float v1 = __half2float(z[(size_t)c1 * WAVE + lane]);
            float v2 = __half2float(z[(size_t)c2 * WAVE + lane]);
            float v3 = __half2float(z[(size_t)c3 * WAVE + lane]);
            float v4 = __half2float(z[(size_t)c4 * WAVE + lane]);
            float v5 = __half2float(z[(size_t)c5 * WAVE + lane]);
            float v6 = __half2float(z[(size_t)c6 * WAVE + lane]);
            float v7 = __half2float(z[(size_t)c7 * WAVE + lane]);
            acc0 += v0 + v1;
            acc1 += v2 + v3;
            acc2 += v4 + v5;
            acc3 += v6 + v7;
        }
        for (; j < n; ++j) {
            int cj = __shfl(c, j);
            acc0 += __half2float(z[(size_t)cj * WAVE + lane]);
        }
    }
    float w = dinv[r];
    zn[(size_t)r * WAVE + lane] = __float2half(w * w * (acc0 + acc1 + acc2 + acc3));
}

// bacc[b] += drt[node] * zn[node]; one thread = 8 k-dims. id over B*8.
__global__ void gather_acc_kernel(const __half* __restrict__ zn,
                                  const float* __restrict__ drt,
                                  const int* __restrict__ users, const int* __restrict__ items,
                                  float* __restrict__ baccU, float* __restrict__ baccI,
                                  int B, int nu) {
    int id = blockIdx.x * blockDim.x + threadIdx.x;
    if (id < B * 8) {
        int b = id >> 3, q = id & 7;
        int u = users[b], it = nu + items[b];
        float wu = drt[u], wi = drt[it];
        uint4 vu = ((const uint4*)(zn))[(size_t)u * 8 + q];
        uint4 vi = ((const uint4*)(zn))[(size_t)it * 8 + q];
        float2 u0 = unpack2(vu.x), u1 = unpack2(vu.y), u2 = unpack2(vu.z), u3 = unpack2(vu.w);
        float2 i0 = unpack2(vi.x), i1 = unpack2(vi.y), i2 = unpack2(vi.z), i3 = unpack2(vi.w);
        float4* bu = (float4*)baccU + (size_t)b * 16 + q * 2;
        float4* bi = (float4*)baccI + (size_t)b * 16 + q * 2;
        float4 a = bu[0];
        a.x += wu * u0.x; a.y += wu * u0.y; a.z += wu * u1.x; a.w += wu * u1.y;
        bu[0] = a;
        a = bu[1];
        a.x += wu * u2.x; a.y += wu * u2.y; a.z += wu * u3.x; a.w += wu * u3.y;
        bu[1] = a;
        a = bi[0];
        a.x += wi * i0.x; a.y += wi * i0.y; a.z += wi * i1.x; a.w += wi * i1.y;
        bi[0] = a;
        a = bi[1];
        a.x += wi * i2.x; a.y += wi * i2.y; a.z += wi * i3.x; a.w += wi * i3.y;
        bi[1] = a;
    }
}

// LDS-tiled fp32 GEMM + fused epilogue.
__global__ __launch_bounds__(256) void proj_out_kernel(const float* __restrict__ baccU,
                                                       const float* __restrict__ baccI,
                                                       const float* __restrict__ Tu,
                                                       const float* __restrict__ F,
                                                       const float* __restrict__ W,
                                                       const float* __restrict__ bvec,
                                                       const int* __restrict__ users,
                                                       const int* __restrict__ items,
                                                       float* __restrict__ out,
                                                       int B, float invL) {
    const int FEATn = 1024;
    __shared__ float Ft[2][32][64];
    __shared__ float Wt[2][32][64];

    int tid = threadIdx.x;
    int tx = tid & 15;        // col group (4 cols)
    int ty = tid >> 4;        // row group (4 rows)
    int r0 = blockIdx.x * 64;

    int lr = tid >> 2;                       // 0..63
    int lq = tid & 3;                        // quad group: local kk 4*lq and 4*lq+16
    int frow = min(r0 + lr, B - 1);
    const float* Fp = F + (size_t)items[frow] * FEATn + lq * 4;
    const float* Wp = W + (size_t)lr * FEATn + lq * 4;

    float4 fa0 = *(const float4*)(Fp);
    float4 fa1 = *(const float4*)(Fp + 16);
    float4 wa0 = *(const float4*)(Wp);
    float4 wa1 = *(const float4*)(Wp + 16);

    float acc[4][4] = {};

    for (int kt = 0; kt < 32; ++kt) {
        int buf = kt & 1;
        #pragma unroll
        for (int i = 0; i < 4; ++i) {
            Ft[buf][lq * 4 + i][lr]      = ((const float*)&fa0)[i];
            Ft[buf][lq * 4 + 16 + i][lr] = ((const float*)&fa1)[i];
            Wt[buf][lq * 4 + i][lr]      = ((const float*)&wa0)[i];
            Wt[buf][lq * 4 + 16 + i][lr] = ((const float*)&wa1)[i];
        }
        __syncthreads();
        if (kt < 31) {
            const float* fp = Fp + (kt + 1) * 32;
            const float* wp = Wp + (kt + 1) * 32;
            fa0 = *(const float4*)(fp);
            fa1 = *(const float4*)(fp + 16);
            wa0 = *(const float4*)(wp);
            wa1 = *(const float4*)(wp + 16);
        }
        #pragma unroll 8
        for (int kk = 0; kk < 32; ++kk) {
            float4 a = *(const float4*)&Ft[buf][kk][ty * 4];
            float4 b = *(const float4*)&Wt[buf][kk][tx * 4];
            acc[0][0] = fmaf(a.x, b.x, acc[0][0]);
            acc[0][1] = fmaf(a.x, b.y, acc[0][1]);
            acc[0][2] = fmaf(a.x, b.z, acc[0][2]);
            acc[0][3] = fmaf(a.x, b.w, acc[0][3]);
            acc[1][0] = fmaf(a.y, b.x, acc[1][0]);
            acc[1][1] = fmaf(a.y, b.y, acc[1][1]);
            acc[1][2] = fmaf(a.y, b.z, acc[1][2]);
            acc[1][3] = fmaf(a.y, b.w, acc[1][3]);
            acc[2][0] = fmaf(a.z, b.x, acc[2][0]);
            acc[2][1] = fmaf(a.z, b.y, acc[2][1]);
            acc[2][2] = fmaf(a.z, b.z, acc[2][2]);
            acc[2][3] = fmaf(a.z, b.w, acc[2][3]);
            acc[3][0] = fmaf(a.w, b.x, acc[3][0]);
            acc[3][1] = fmaf(a.w, b.y, acc[3][1]);
            acc[3][2] = fmaf(a.w, b.z, acc[3][2]);
            acc[3][3] = fmaf(a.w, b.w, acc[3][3]);
        }
    }

    float4 bb = *(const float4*)(bvec + tx * 4);
    float L2 = invL * invL;
    float res[4];
    #pragma unroll
    for (int r = 0; r < 4; ++r) {
        int gr = min(r0 + ty * 4 + r, B - 1);
        float pb0 = acc[r][0] + bb.x;
        float pb1 = acc[r][1] + bb.y;
        float pb2 = acc[r][2] + bb.z;
        float pb3 = acc[r][3] + bb.w;
        float s = pb0 * pb0 + pb1 * pb1 + pb2 * pb2 + pb3 * pb3;
        #pragma unroll
        for (int d = 1; d < 16; d <<= 1) s += __shfl_xor(s, d, 64);
        float inv = 1.0f / fmaxf(sqrtf(s), 1e-12f);
        int u = users[gr];
        float4 tu = *(const float4*)(Tu + (size_t)u * WAVE + tx * 4);
        float4 gu = *(const float4*)(baccU + (size_t)gr * WAVE + tx * 4);
        float4 gi = *(const float4*)(baccI + (size_t)gr * WAVE + tx * 4);
        float dsum = L2 * (gu.x * gi.x + gu.y * gi.y + gu.z * gi.z + gu.w * gi.w)
                   + inv * (tu.x * pb0 + tu.y * pb1 + tu.z * pb2 + tu.w * pb3);
        #pragma unroll
        for (int d = 1; d < 16; d <<= 1) dsum += __shfl_xor(dsum, d, 64);
        res[r] = dsum;
    }
    if (tx == 0) {
        #pragma unroll
        for (int r = 0; r < 4; ++r) {
            int gr = r0 + ty * 4 + r;
            if (gr < B) out[gr] = res[r];
        }
    }
}

extern "C" void kernel_launch(void* const* d_in, const int* in_sizes, int n_in,
                              void* d_out, int out_size, void* d_ws, size_t ws_size,
                              hipStream_t stream) {
    const float* Gu = (const float*)d_in[0];
    const float* Gi = (const float*)d_in[1];
    const float* Tu = (const float*)d_in[2];
    const float* F  = (const float*)d_in[3];
    const float* W  = (const float*)d_in[4];
    const float* bv = (const float*)d_in[5];
    const int* ue    = (const int*)d_in[6];
    const int* ie    = (const int*)d_in[7];
    const int* users = (const int*)d_in[8];
    const int* items = (const int*)d_in[9];
    float* out = (float*)d_out;

    const int K  = 64;
    const int nu = in_sizes[0] / K;
    const int ni = in_sizes[1] / K;
    const int N  = nu + ni;
    const int E  = in_sizes[6];
    const int B  = in_sizes[8];

    char* p = (char*)d_ws;
    auto alloc = [&](size_t bytes) -> void* {
        void* r = (void*)p;
        p += (bytes + 255) & ~(size_t)255;
        return r;
    };
    float* dinv   = (float*)alloc((size_t)N * 4);
    float* drt    = (float*)alloc((size_t)N * 4);
    int*   offs   = (int*)  alloc((size_t)(N + 1) * 4);
    int*   flags  = (int*)  alloc((size_t)N * 4);
    int*   col    = (int*)  alloc((size_t)2 * E * 4);
    __half* za    = (__half*)alloc((size_t)N * K * 2);
    __half* zb    = (__half*)alloc((size_t)N * K * 2);
    float* baccU  = (float*)alloc((size_t)B * K * 4);
    float* baccI  = (float*)alloc((size_t)B * K * 4);
    int*   list   = (int*)  alloc((size_t)2 * B * 4);
    int*   cnt    = (int*)  alloc(256);
    int*   bcnt   = (int*)  alloc((size_t)NBMAX * 4);
    int*   pbase  = (int*)  alloc((size_t)NBMAX * 4);
    int*   pcur   = (int*)  alloc((size_t)NBMAX * 4);

    // bucket geometry: 256 nodes/bucket (shift 8) for this problem size
    int shift = 8;
    while (((N + (1 << shift) - 1) >> shift) > NBMAX) ++shift;
    const int NB = (N + (1 << shift) - 1) >> shift;

    // packed pair staging (2E ints = 24MB) aliases za+zb (38.4MB fp16):
    // pairs are dead before init_z writes za.
    int* pairs = (int*)za;

    const int NG   = (E + 3) / 4;            // int4 edge groups
    const int gpbH = (NG + 1023) / 1024;     // groups per bhist block
    const int nbS  = (NG + ETG - 1) / ETG;   // scatter blocks

    // graph build
    hipMemsetAsync(bcnt, 0, (size_t)NB * 4, stream);
    bhist_kernel<<<1024, 256, 0, stream>>>(ue, ie, bcnt, E, nu, NB, shift, gpbH, NG);
    bscan_kernel<<<1, 1024, 0, stream>>>(bcnt, pbase, pcur, NB);
    scatter_kernel<<<nbS, 256, 0, stream>>>(ue, ie, pcur, pairs, E, nu, shift, NB, NG);
    build_kernel<<<NB, 256, 0, stream>>>(pairs, pbase, pcur, offs, dinv, drt, col,
                                         N, shift, NB, 2 * E);

    // batch-node list
    hipMemsetAsync(flags, 0, (size_t)N * 4, stream);
    hipMemsetAsync(cnt, 0, 4, stream);
    mark_kernel<<<(B + 255) / 256, 256, 0, stream>>>(users, items, flags, B, nu);
    compact_kernel<<<(N + 255) / 256, 256, 0, stream>>>(flags, list, cnt, N);

    // init
    init_z_kernel<<<(N * 8 + 255) / 256, 256, 0, stream>>>(Gu, Gi, dinv, za, nu, N);
    init_bacc_kernel<<<(B * 16 + 255) / 256, 256, 0, stream>>>(Gu, Gi, users, items,
                                                               baccU, baccI, B);

    // layer 1 (full)
    pull_kernel<<<(N + 3) / 4, 256, 0, stream>>>(za, zb, offs, col, dinv,
                                                 nullptr, nullptr, N);
    gather_acc_kernel<<<(B * 8 + 255) / 256, 256, 0, stream>>>(zb, drt, users, items,
                                                               baccU, baccI, B, nu);
    // layer 2 (full)
    pull_kernel<<<(N + 3) / 4, 256, 0, stream>>>(zb, za, offs, col, dinv,
                                                 nullptr, nullptr, N);
    gather_acc_kernel<<<(B * 8 + 255) / 256, 256, 0, stream>>>(za, drt, users, items,
                                                               baccU, baccI, B, nu);
    // layer 3 (sparse: only unique batch rows)
    pull_kernel<<<(2 * B + 3) / 4, 256, 0, stream>>>(za, zb, offs, col, dinv,
                                                     list, cnt, N);
    gather_acc_kernel<<<(B * 8 + 255) / 256, 256, 0, stream>>>(zb, drt, users, items,
                                                               baccU, baccI, B, nu);

    // epilogue: LDS-tiled GEMM + fused norm/dots
    proj_out_kernel<<<(B + 63) / 64, 256, 0, stream>>>(baccU, baccI, Tu, F, W, bv,
                                                       users, items, out, B, 0.25f);
}

// Round 5
// 732.779 us; speedup vs baseline: 2.1750x; 1.0583x over previous
//
#include <hip/hip_runtime.h>
#include <hip/hip_bf16.h>
#include <hip/hip_fp16.h>

// LightGCN forward on MI355X.
// R10: vectorized pull gather. R9 (fp16 z) shifted pull from traffic-bound
//      (45% HBM) to instruction-bound: 26% HBM, 60% VALU -- per neighbor we
//      paid 1 ushort load inst + shfl + 64b addr + cvt + add. R10 transposes
//      the lane map: lane = (neighbor-slot l>>3, k-quad l&7), each lane loads
//      uint4 (8 halves); one dwordx4 per wave covers 8 neighbor rows. ~8x
//      fewer VMEM insts, ~2.5x fewer VALU/neighbor; fp32 accum kept; 3-round
//      shfl_xor (stride 8/16/32) reduces neighbor-slots at row end; lanes 0-7
//      store the 128B row. Everything else unchanged from R9.

#define WAVE 64
#define NBMAX 592   // max dst buckets; shift grows until NB <= NBMAX
#define SLOTS 14336 // pairs per scatter block (= 2 * 7168 edges)
#define ETG 1792    // int4 edge groups per scatter block (7168 edges)

typedef int nt_int4 __attribute__((ext_vector_type(4)));

__device__ __forceinline__ unsigned pack2(float lo, float hi) {
    __half2 h = __floats2half2_rn(lo, hi);
    return *(unsigned*)&h;
}
__device__ __forceinline__ float2 unpack2(unsigned u) {
    __half2 h = *(__half2*)&u;
    return __half22float2(h);
}

// --- pass 1: per-bucket pair counts (edges read once) --------------------
__global__ __launch_bounds__(256) void bhist_kernel(const int* __restrict__ ue,
                                                    const int* __restrict__ ie,
                                                    int* __restrict__ bcnt,
                                                    int E, int nu, int NB, int shift,
                                                    int gpb, int NG) {
    __shared__ int lh[NBMAX];
    int tid = threadIdx.x;
    for (int b = tid; b < NB; b += 256) lh[b] = 0;
    __syncthreads();
    int g0 = blockIdx.x * gpb;
    int g1 = min(g0 + gpb, NG);
    for (int g = g0 + tid; g < g1; g += 256) {
        int e0 = g * 4;
        if (e0 + 3 < E) {
            nt_int4 u = __builtin_nontemporal_load((const nt_int4*)(ue + e0));
            nt_int4 v = __builtin_nontemporal_load((const nt_int4*)(ie + e0));
            atomicAdd(&lh[(nu + v.x) >> shift], 1); atomicAdd(&lh[u.x >> shift], 1);
            atomicAdd(&lh[(nu + v.y) >> shift], 1); atomicAdd(&lh[u.y >> shift], 1);
            atomicAdd(&lh[(nu + v.z) >> shift], 1); atomicAdd(&lh[u.z >> shift], 1);
            atomicAdd(&lh[(nu + v.w) >> shift], 1); atomicAdd(&lh[u.w >> shift], 1);
        } else {
            for (int e = e0; e < E; ++e) {
                atomicAdd(&lh[(nu + ie[e]) >> shift], 1);
                atomicAdd(&lh[ue[e] >> shift], 1);
            }
        }
    }
    __syncthreads();
    for (int b = tid; b < NB; b += 256) if (lh[b]) atomicAdd(&bcnt[b], lh[b]);
}

// --- pass 2: exclusive scan over NB bucket counts ------------------------
__global__ __launch_bounds__(1024) void bscan_kernel(const int* __restrict__ bcnt,
                                                     int* __restrict__ pbase,
                                                     int* __restrict__ pcur, int NB) {
    __shared__ int wsum[16];
    int t = threadIdx.x;
    int v0 = (t < NB) ? bcnt[t] : 0;
    int lane = t & 63, w = t >> 6;
    int v = v0;
    #pragma unroll
    for (int d = 1; d < 64; d <<= 1) {
        int o = __shfl_up(v, d, 64);
        if (lane >= d) v += o;
    }
    if (lane == 63) wsum[w] = v;
    __syncthreads();
    if (t == 0) {
        int r = 0;
        #pragma unroll
        for (int k = 0; k < 16; ++k) { int s = wsum[k]; wsum[k] = r; r += s; }
    }
    __syncthreads();
    int excl = (v - v0) + wsum[w];
    if (t < NB) { pbase[t] = excl; pcur[t] = excl; }
}

// --- pass 3: block-local counting-sort partition -------------------------
__global__ __launch_bounds__(256) void scatter_kernel(const int* __restrict__ ue,
                                                      const int* __restrict__ ie,
                                                      int* __restrict__ pcur,
                                                      int* __restrict__ pairs,
                                                      int E, int nu, int shift,
                                                      int NB, int NG) {
    __shared__ int slot[SLOTS];
    __shared__ int lhist[NBMAX];
    __shared__ int lcur[NBMAX];
    __shared__ int gbase[NBMAX];
    int tid = threadIdx.x;
    for (int b = tid; b < NB; b += 256) lhist[b] = 0;
    __syncthreads();
    int g0 = blockIdx.x * ETG;
    int g1 = min(g0 + ETG, NG);
    int mask = (1 << shift) - 1;
    // pass A: count
    for (int g = g0 + tid; g < g1; g += 256) {
        int e0 = g * 4;
        if (e0 + 3 < E) {
            nt_int4 u = __builtin_nontemporal_load((const nt_int4*)(ue + e0));
            nt_int4 v = __builtin_nontemporal_load((const nt_int4*)(ie + e0));
            atomicAdd(&lhist[(nu + v.x) >> shift], 1); atomicAdd(&lhist[u.x >> shift], 1);
            atomicAdd(&lhist[(nu + v.y) >> shift], 1); atomicAdd(&lhist[u.y >> shift], 1);
            atomicAdd(&lhist[(nu + v.z) >> shift], 1); atomicAdd(&lhist[u.z >> shift], 1);
            atomicAdd(&lhist[(nu + v.w) >> shift], 1); atomicAdd(&lhist[u.w >> shift], 1);
        } else {
            for (int e = e0; e < E; ++e) {
                atomicAdd(&lhist[(nu + ie[e]) >> shift], 1);
                atomicAdd(&lhist[ue[e] >> shift], 1);
            }
        }
    }
    __syncthreads();
    // exclusive scan of lhist -> lcur (wave 0, chunks of 64 with carry)
    if (tid < 64) {
        int carry = 0;
        for (int c = 0; c < NB; c += 64) {
            int idx = c + tid;
            int x = (idx < NB) ? lhist[idx] : 0;
            int v = x;
            #pragma unroll
            for (int d = 1; d < 64; d <<= 1) {
                int o = __shfl_up(v, d, 64);
                if (tid >= d) v += o;
            }
            if (idx < NB) lcur[idx] = v - x + carry;
            carry += __shfl(v, 63, 64);
        }
    }
    __syncthreads();
    // one global reservation per non-empty bucket
    for (int b = tid; b < NB; b += 256) {
        int c = lhist[b];
        if (c) gbase[b] = atomicAdd(&pcur[b], c);
    }
    // pass B: place into bucket-contiguous LDS slots
    for (int g = g0 + tid; g < g1; g += 256) {
        int e0 = g * 4;
        if (e0 + 3 < E) {
            nt_int4 u = __builtin_nontemporal_load((const nt_int4*)(ue + e0));
            nt_int4 v = __builtin_nontemporal_load((const nt_int4*)(ie + e0));
            int uu[4] = {u.x, u.y, u.z, u.w};
            int vv[4] = {nu + v.x, nu + v.y, nu + v.z, nu + v.w};
            #pragma unroll
            for (int t = 0; t < 4; ++t) {
                int d = vv[t], s = uu[t];
                int p = atomicAdd(&lcur[d >> shift], 1);
                slot[p] = ((d & mask) << 18) | s;
                d = uu[t]; s = vv[t];
                p = atomicAdd(&lcur[d >> shift], 1);
                slot[p] = ((d & mask) << 18) | s;
            }
        } else {
            for (int e = e0; e < E; ++e) {
                int d = nu + ie[e], s = ue[e];
                int p = atomicAdd(&lcur[d >> shift], 1);
                slot[p] = ((d & mask) << 18) | s;
                d = ue[e]; s = nu + ie[e];
                p = atomicAdd(&lcur[d >> shift], 1);
                slot[p] = ((d & mask) << 18) | s;
            }
        }
    }
    __syncthreads();
    // write out runs: one wave per bucket, strided; coalesced within run
    int w = tid >> 6, lane = tid & 63;
    for (int b = w; b < NB; b += 4) {
        int c = lhist[b];
        if (!c) continue;
        int start = lcur[b] - c;   // cursor ended at start + c
        int gb = gbase[b];
        for (int i = lane; i < c; i += 64)
            pairs[gb + i] = slot[start + i];
    }
}

// --- pass 4: per-bucket CSR build (deg hist + local scan + scatter) ------
__global__ __launch_bounds__(256) void build_kernel(const int* __restrict__ pairs,
                                                    const int* __restrict__ pbase,
                                                    const int* __restrict__ pcur,
                                                    int* __restrict__ offs,
                                                    float* __restrict__ dinv,
                                                    float* __restrict__ drt,
                                                    int* __restrict__ col,
                                                    int N, int shift, int NB, int twoE) {
    __shared__ int dcnt[512];
    __shared__ int ex[512];
    __shared__ int cur[512];
    int b = blockIdx.x, tid = threadIdx.x;
    int lo = b << shift;
    int n = min(1 << shift, N - lo);
    for (int i = tid; i < 512; i += 256) dcnt[i] = 0;
    __syncthreads();
    int pb = pbase[b];
    int cnt = pcur[b] - pb;
    for (int i = tid; i < cnt; i += 256) {
        int p = pairs[pb + i];
        atomicAdd(&dcnt[p >> 18], 1);
    }
    __syncthreads();
    if (tid < 64) {
        int base = tid * 8;
        int loc[8]; int s = 0;
        #pragma unroll
        for (int k = 0; k < 8; ++k) { loc[k] = s; s += dcnt[base + k]; }
        int v = s;
        #pragma unroll
        for (int d = 1; d < 64; d <<= 1) {
            int o = __shfl_up(v, d, 64);
            if (tid >= d) v += o;
        }
        int excl = v - s;
        #pragma unroll
        for (int k = 0; k < 8; ++k) ex[base + k] = excl + loc[k];
    }
    __syncthreads();
    for (int i = tid; i < n; i += 256) {
        int c = pb + ex[i];
        cur[i] = c;
        offs[lo + i] = c;
        int d = dcnt[i];
        dinv[lo + i] = (d > 0) ? rsqrtf((float)d) : 0.0f;
        drt[lo + i]  = (d > 0) ? sqrtf((float)d)  : 0.0f;
    }
    if (b == NB - 1 && tid == 0) offs[N] = twoE;
    __syncthreads();
    for (int i = tid; i < cnt; i += 256) {
        int p = pairs[pb + i];
        int pos = atomicAdd(&cur[p >> 18], 1);
        col[pos] = p & 0x3FFFF;
    }
}

// --- batch-node marking / compaction -------------------------------------
__global__ void mark_kernel(const int* __restrict__ users, const int* __restrict__ items,
                            int* __restrict__ flag, int B, int nu) {
    int b = blockIdx.x * blockDim.x + threadIdx.x;
    if (b < B) {
        flag[users[b]] = 1;
        flag[nu + items[b]] = 1;
    }
}

__global__ void compact_kernel(const int* __restrict__ flag, int* __restrict__ list,
                               int* __restrict__ cnt, int N) {
    int n = blockIdx.x * blockDim.x + threadIdx.x;
    if (n < N && flag[n]) {
        int pos = atomicAdd(cnt, 1);
        list[pos] = n;
    }
}

// z init: za[n][k] = dinv[n] * x0[n][k], stored fp16. One thread = 8 k-dims
// (16B store). id over N*8.
__global__ void init_z_kernel(const float* __restrict__ Gu, const float* __restrict__ Gi,
                              const float* __restrict__ dinv,
                              __half* __restrict__ z, int nu, int N) {
    int id = blockIdx.x * blockDim.x + threadIdx.x;
    if (id < N * 8) {
        int n = id >> 3, q = id & 7;
        const float4* src = (n < nu) ? (const float4*)Gu : (const float4*)Gi;
        int j = (n < nu) ? n : n - nu;
        float4 a0 = src[(size_t)j * 16 + q * 2];
        float4 a1 = src[(size_t)j * 16 + q * 2 + 1];
        float w = dinv[n];
        uint4 o;
        o.x = pack2(a0.x * w, a0.y * w);
        o.y = pack2(a0.z * w, a0.w * w);
        o.z = pack2(a1.x * w, a1.y * w);
        o.w = pack2(a1.z * w, a1.w * w);
        ((uint4*)z)[id] = o;
    }
}

__global__ void init_bacc_kernel(const float* __restrict__ Gu, const float* __restrict__ Gi,
                                 const int* __restrict__ users, const int* __restrict__ items,
                                 float* __restrict__ baccU, float* __restrict__ baccI, int B) {
    int id = blockIdx.x * blockDim.x + threadIdx.x;  // B*16 float4 slots
    if (id < B * 16) {
        int b = id >> 4, q = id & 15;
        ((float4*)baccU)[id] = ((const float4*)Gu)[(size_t)users[b] * 16 + q];
        ((float4*)baccI)[id] = ((const float4*)Gi)[(size_t)items[b] * 16 + q];
    }
}

// One wave per destination row, vectorized gather:
// lane = (neighbor-slot s=lane>>3, k-quad q=lane&7); each lane loads uint4
// (8 halves) of neighbor s's row -> one dwordx4 covers 8 neighbor rows.
// fp32 accum; stride-8/16/32 shfl_xor reduces slots; lanes 0-7 store 128B row.
__global__ __launch_bounds__(256) void pull_kernel(const __half* __restrict__ z,
                                                   __half* __restrict__ zn,
                                                   const int* __restrict__ offs,
                                                   const int* __restrict__ col,
                                                   const float* __restrict__ dinv,
                                                   const int* __restrict__ rows,
                                                   const int* __restrict__ n_ptr, int N) {
    int wid = (blockIdx.x * blockDim.x + threadIdx.x) >> 6;
    int lane = threadIdx.x & 63;
    int nrows = rows ? *n_ptr : N;
    if (wid >= nrows) return;
    int r = rows ? rows[wid] : wid;
    int s = offs[r], e = offs[r + 1];
    int slot = lane >> 3;   // neighbor sub-slot 0..7
    int q    = lane & 7;    // k-quad: halves [8q, 8q+8)
    float a0 = 0.f, a1 = 0.f, a2 = 0.f, a3 = 0.f;
    float a4 = 0.f, a5 = 0.f, a6 = 0.f, a7 = 0.f;
    for (int base = s; base < e; base += 64) {
        int idx = base + lane;
        int c = (idx < e) ? __builtin_nontemporal_load(col + idx) : 0;
        int n = min(64, e - base);
        int nfull = n & ~7;
        int j = 0;
        for (; j < nfull; j += 8) {
            int cj = __shfl(c, j + slot);
            uint4 v = ((const uint4*)(z + (size_t)cj * WAVE))[q];
            float2 f0 = unpack2(v.x), f1 = unpack2(v.y);
            float2 f2 = unpack2(v.z), f3 = unpack2(v.w);
            a0 += f0.x; a1 += f0.y; a2 += f1.x; a3 += f1.y;
            a4 += f2.x; a5 += f2.y; a6 += f3.x; a7 += f3.y;
        }
        if (j < n) {
            int take = n - j;                       // 1..7 (wave-uniform)
            int cj = __shfl(c, j + (slot < take ? slot : 0));
            uint4 v = ((const uint4*)(z + (size_t)cj * WAVE))[q];
            if (slot < take) {
                float2 f0 = unpack2(v.x), f1 = unpack2(v.y);
                float2 f2 = unpack2(v.z), f3 = unpack2(v.w);
                a0 += f0.x; a1 += f0.y; a2 += f1.x; a3 += f1.y;
                a4 += f2.x; a5 += f2.y; a6 += f3.x; a7 += f3.y;
            }
        }
    }
    // reduce neighbor-slots: lanes {l, l^8, l^16, l^32} share k-quad q
    #pragma unroll
    for (int d = 8; d < 64; d <<= 1) {
        a0 += __shfl_xor(a0, d, 64); a1 += __shfl_xor(a1, d, 64);
        a2 += __shfl_xor(a2, d, 64); a3 += __shfl_xor(a3, d, 64);
        a4 += __shfl_xor(a4, d, 64); a5 += __shfl_xor(a5, d, 64);
        a6 += __shfl_xor(a6, d, 64); a7 += __shfl_xor(a7, d, 64);
    }
    if (slot == 0) {
        float w = dinv[r];
        float ww = w * w;
        uint4 o;
        o.x = pack2(a0 * ww, a1 * ww);
        o.y = pack2(a2 * ww, a3 * ww);
        o.z = pack2(a4 * ww, a5 * ww);
        o.w = pack2(a6 * ww, a7 * ww);
        ((uint4*)(zn + (size_t)r * WAVE))[q] = o;
    }
}

// bacc[b] += drt[node] * zn[node]; one thread = 8 k-dims. id over B*8.
__global__ void gather_acc_kernel(const __half* __restrict__ zn,
                                  const float* __restrict__ drt,
                                  const int* __restrict__ users, const int* __restrict__ items,
                                  float* __restrict__ baccU, float* __restrict__ baccI,
                                  int B, int nu) {
    int id = blockIdx.x * blockDim.x + threadIdx.x;
    if (id < B * 8) {
        int b = id >> 3, q = id & 7;
        int u = users[b], it = nu + items[b];
        float wu = drt[u], wi = drt[it];
        uint4 vu = ((const uint4*)(zn))[(size_t)u * 8 + q];
        uint4 vi = ((const uint4*)(zn))[(size_t)it * 8 + q];
        float2 u0 = unpack2(vu.x), u1 = unpack2(vu.y), u2 = unpack2(vu.z), u3 = unpack2(vu.w);
        float2 i0 = unpack2(vi.x), i1 = unpack2(vi.y), i2 = unpack2(vi.z), i3 = unpack2(vi.w);
        float4* bu = (float4*)baccU + (size_t)b * 16 + q * 2;
        float4* bi = (float4*)baccI + (size_t)b * 16 + q * 2;
        float4 a = bu[0];
        a.x += wu * u0.x; a.y += wu * u0.y; a.z += wu * u1.x; a.w += wu * u1.y;
        bu[0] = a;
        a = bu[1];
        a.x += wu * u2.x; a.y += wu * u2.y; a.z += wu * u3.x; a.w += wu * u3.y;
        bu[1] = a;
        a = bi[0];
        a.x += wi * i0.x; a.y += wi * i0.y; a.z += wi * i1.x; a.w += wi * i1.y;
        bi[0] = a;
        a = bi[1];
        a.x += wi * i2.x; a.y += wi * i2.y; a.z += wi * i3.x; a.w += wi * i3.y;
        bi[1] = a;
    }
}

// LDS-tiled fp32 GEMM + fused epilogue.
__global__ __launch_bounds__(256) void proj_out_kernel(const float* __restrict__ baccU,
                                                       const float* __restrict__ baccI,
                                                       const float* __restrict__ Tu,
                                                       const float* __restrict__ F,
                                                       const float* __restrict__ W,
                                                       const float* __restrict__ bvec,
                                                       const int* __restrict__ users,
                                                       const int* __restrict__ items,
                                                       float* __restrict__ out,
                                                       int B, float invL) {
    const int FEATn = 1024;
    __shared__ float Ft[2][32][64];
    __shared__ float Wt[2][32][64];

    int tid = threadIdx.x;
    int tx = tid & 15;        // col group (4 cols)
    int ty = tid >> 4;        // row group (4 rows)
    int r0 = blockIdx.x * 64;

    int lr = tid >> 2;                       // 0..63
    int lq = tid & 3;                        // quad group: local kk 4*lq and 4*lq+16
    int frow = min(r0 + lr, B - 1);
    const float* Fp = F + (size_t)items[frow] * FEATn + lq * 4;
    const float* Wp = W + (size_t)lr * FEATn + lq * 4;

    float4 fa0 = *(const float4*)(Fp);
    float4 fa1 = *(const float4*)(Fp + 16);
    float4 wa0 = *(const float4*)(Wp);
    float4 wa1 = *(const float4*)(Wp + 16);

    float acc[4][4] = {};

    for (int kt = 0; kt < 32; ++kt) {
        int buf = kt & 1;
        #pragma unroll
        for (int i = 0; i < 4; ++i) {
            Ft[buf][lq * 4 + i][lr]      = ((const float*)&fa0)[i];
            Ft[buf][lq * 4 + 16 + i][lr] = ((const float*)&fa1)[i];
            Wt[buf][lq * 4 + i][lr]      = ((const float*)&wa0)[i];
            Wt[buf][lq * 4 + 16 + i][lr] = ((const float*)&wa1)[i];
        }
        __syncthreads();
        if (kt < 31) {
            const float* fp = Fp + (kt + 1) * 32;
            const float* wp = Wp + (kt + 1) * 32;
            fa0 = *(const float4*)(fp);
            fa1 = *(const float4*)(fp + 16);
            wa0 = *(const float4*)(wp);
            wa1 = *(const float4*)(wp + 16);
        }
        #pragma unroll 8
        for (int kk = 0; kk < 32; ++kk) {
            float4 a = *(const float4*)&Ft[buf][kk][ty * 4];
            float4 b = *(const float4*)&Wt[buf][kk][tx * 4];
            acc[0][0] = fmaf(a.x, b.x, acc[0][0]);
            acc[0][1] = fmaf(a.x, b.y, acc[0][1]);
            acc[0][2] = fmaf(a.x, b.z, acc[0][2]);
            acc[0][3] = fmaf(a.x, b.w, acc[0][3]);
            acc[1][0] = fmaf(a.y, b.x, acc[1][0]);
            acc[1][1] = fmaf(a.y, b.y, acc[1][1]);
            acc[1][2] = fmaf(a.y, b.z, acc[1][2]);
            acc[1][3] = fmaf(a.y, b.w, acc[1][3]);
            acc[2][0] = fmaf(a.z, b.x, acc[2][0]);
            acc[2][1] = fmaf(a.z, b.y, acc[2][1]);
            acc[2][2] = fmaf(a.z, b.z, acc[2][2]);
            acc[2][3] = fmaf(a.z, b.w, acc[2][3]);
            acc[3][0] = fmaf(a.w, b.x, acc[3][0]);
            acc[3][1] = fmaf(a.w, b.y, acc[3][1]);
            acc[3][2] = fmaf(a.w, b.z, acc[3][2]);
            acc[3][3] = fmaf(a.w, b.w, acc[3][3]);
        }
    }

    float4 bb = *(const float4*)(bvec + tx * 4);
    float L2 = invL * invL;
    float res[4];
    #pragma unroll
    for (int r = 0; r < 4; ++r) {
        int gr = min(r0 + ty * 4 + r, B - 1);
        float pb0 = acc[r][0] + bb.x;
        float pb1 = acc[r][1] + bb.y;
        float pb2 = acc[r][2] + bb.z;
        float pb3 = acc[r][3] + bb.w;
        float s = pb0 * pb0 + pb1 * pb1 + pb2 * pb2 + pb3 * pb3;
        #pragma unroll
        for (int d = 1; d < 16; d <<= 1) s += __shfl_xor(s, d, 64);
        float inv = 1.0f / fmaxf(sqrtf(s), 1e-12f);
        int u = users[gr];
        float4 tu = *(const float4*)(Tu + (size_t)u * WAVE + tx * 4);
        float4 gu = *(const float4*)(baccU + (size_t)gr * WAVE + tx * 4);
        float4 gi = *(const float4*)(baccI + (size_t)gr * WAVE + tx * 4);
        float dsum = L2 * (gu.x * gi.x + gu.y * gi.y + gu.z * gi.z + gu.w * gi.w)
                   + inv * (tu.x * pb0 + tu.y * pb1 + tu.z * pb2 + tu.w * pb3);
        #pragma unroll
        for (int d = 1; d < 16; d <<= 1) dsum += __shfl_xor(dsum, d, 64);
        res[r] = dsum;
    }
    if (tx == 0) {
        #pragma unroll
        for (int r = 0; r < 4; ++r) {
            int gr = r0 + ty * 4 + r;
            if (gr < B) out[gr] = res[r];
        }
    }
}

extern "C" void kernel_launch(void* const* d_in, const int* in_sizes, int n_in,
                              void* d_out, int out_size, void* d_ws, size_t ws_size,
                              hipStream_t stream) {
    const float* Gu = (const float*)d_in[0];
    const float* Gi = (const float*)d_in[1];
    const float* Tu = (const float*)d_in[2];
    const float* F  = (const float*)d_in[3];
    const float* W  = (const float*)d_in[4];
    const float* bv = (const float*)d_in[5];
    const int* ue    = (const int*)d_in[6];
    const int* ie    = (const int*)d_in[7];
    const int* users = (const int*)d_in[8];
    const int* items = (const int*)d_in[9];
    float* out = (float*)d_out;

    const int K  = 64;
    const int nu = in_sizes[0] / K;
    const int ni = in_sizes[1] / K;
    const int N  = nu + ni;
    const int E  = in_sizes[6];
    const int B  = in_sizes[8];

    char* p = (char*)d_ws;
    auto alloc = [&](size_t bytes) -> void* {
        void* r = (void*)p;
        p += (bytes + 255) & ~(size_t)255;
        return r;
    };
    float* dinv   = (float*)alloc((size_t)N * 4);
    float* drt    = (float*)alloc((size_t)N * 4);
    int*   offs   = (int*)  alloc((size_t)(N + 1) * 4);
    int*   flags  = (int*)  alloc((size_t)N * 4);
    int*   col    = (int*)  alloc((size_t)2 * E * 4);
    __half* za    = (__half*)alloc((size_t)N * K * 2);
    __half* zb    = (__half*)alloc((size_t)N * K * 2);
    float* baccU  = (float*)alloc((size_t)B * K * 4);
    float* baccI  = (float*)alloc((size_t)B * K * 4);
    int*   list   = (int*)  alloc((size_t)2 * B * 4);
    int*   cnt    = (int*)  alloc(256);
    int*   bcnt   = (int*)  alloc((size_t)NBMAX * 4);
    int*   pbase  = (int*)  alloc((size_t)NBMAX * 4);
    int*   pcur   = (int*)  alloc((size_t)NBMAX * 4);

    // bucket geometry: 256 nodes/bucket (shift 8) for this problem size
    int shift = 8;
    while (((N + (1 << shift) - 1) >> shift) > NBMAX) ++shift;
    const int NB = (N + (1 << shift) - 1) >> shift;

    // packed pair staging (2E ints = 24MB) aliases za+zb (38.4MB fp16):
    // pairs are dead before init_z writes za.
    int* pairs = (int*)za;

    const int NG   = (E + 3) / 4;            // int4 edge groups
    const int gpbH = (NG + 1023) / 1024;     // groups per bhist block
    const int nbS  = (NG + ETG - 1) / ETG;   // scatter blocks

    // graph build
    hipMemsetAsync(bcnt, 0, (size_t)NB * 4, stream);
    bhist_kernel<<<1024, 256, 0, stream>>>(ue, ie, bcnt, E, nu, NB, shift, gpbH, NG);
    bscan_kernel<<<1, 1024, 0, stream>>>(bcnt, pbase, pcur, NB);
    scatter_kernel<<<nbS, 256, 0, stream>>>(ue, ie, pcur, pairs, E, nu, shift, NB, NG);
    build_kernel<<<NB, 256, 0, stream>>>(pairs, pbase, pcur, offs, dinv, drt, col,
                                         N, shift, NB, 2 * E);

    // batch-node list
    hipMemsetAsync(flags, 0, (size_t)N * 4, stream);
    hipMemsetAsync(cnt, 0, 4, stream);
    mark_kernel<<<(B + 255) / 256, 256, 0, stream>>>(users, items, flags, B, nu);
    compact_kernel<<<(N + 255) / 256, 256, 0, stream>>>(flags, list, cnt, N);

    // init
    init_z_kernel<<<(N * 8 + 255) / 256, 256, 0, stream>>>(Gu, Gi, dinv, za, nu, N);
    init_bacc_kernel<<<(B * 16 + 255) / 256, 256, 0, stream>>>(Gu, Gi, users, items,
                                                               baccU, baccI, B);

    // layer 1 (full)
    pull_kernel<<<(N + 3) / 4, 256, 0, stream>>>(za, zb, offs, col, dinv,
                                                 nullptr, nullptr, N);
    gather_acc_kernel<<<(B * 8 + 255) / 256, 256, 0, stream>>>(zb, drt, users, items,
                                                               baccU, baccI, B, nu);
    // layer 2 (full)
    pull_kernel<<<(N + 3) / 4, 256, 0, stream>>>(zb, za, offs, col, dinv,
                                                 nullptr, nullptr, N);
    gather_acc_kernel<<<(B * 8 + 255) / 256, 256, 0, stream>>>(za, drt, users, items,
                                                               baccU, baccI, B, nu);
    // layer 3 (sparse: only unique batch rows)
    pull_kernel<<<(2 * B + 3) / 4, 256, 0, stream>>>(za, zb, offs, col, dinv,
                                                     list, cnt, N);
    gather_acc_kernel<<<(B * 8 + 255) / 256, 256, 0, stream>>>(zb, drt, users, items,
                                                               baccU, baccI, B, nu);

    // epilogue: LDS-tiled GEMM + fused norm/dots
    proj_out_kernel<<<(B + 63) / 64, 256, 0, stream>>>(baccU, baccI, Tu, F, W, bv,
                                                       users, items, out, B, 0.25f);
}

// Round 6
// 700.632 us; speedup vs baseline: 2.2747x; 1.0459x over previous
//
#include <hip/hip_runtime.h>
#include <hip/hip_bf16.h>
#include <hip/hip_fp16.h>

// LightGCN forward on MI355X.
// R11: deterministic graph build + pipelined pull.
//      R10 profiling is polluted by the harness's 800MB workspace re-poison
//      (fillBufferAligned, ~121us/iter, 84% HBM peak -- inside the timed
//      region, untouchable). All our kernels are now <121us. Two changes:
//      (1) build chain: bhist+bscan+scatter (edges read 3x, 36M LDS atomics,
//          contended global pcur) -> histA (per-block hist row to global bh
//          matrix) + colscan/bscan (exact per-(block,bucket) bases) + place
//          (reloads its 2.4KB hist row instead of re-histogramming 14K edges;
//          writes runs at precomputed bases). Edges 2x, LDS atomics 24M,
//          zero global atomics, deterministic.
//      (2) pull: explicit 2-deep load pipeline (next uint4 issued before
//          consuming current) to force >=2 VMEM in flight per lane.

#define WAVE 64
#define NBMAX 592   // max dst buckets; shift grows until NB <= NBMAX
#define SLOTS 14336 // pairs per scatter block (= 2 * 7168 edges)
#define ETG 1792    // int4 edge groups per scatter block (7168 edges)

typedef int nt_int4 __attribute__((ext_vector_type(4)));

__device__ __forceinline__ unsigned pack2(float lo, float hi) {
    __half2 h = __floats2half2_rn(lo, hi);
    return *(unsigned*)&h;
}
__device__ __forceinline__ float2 unpack2(unsigned u) {
    __half2 h = *(__half2*)&u;
    return __half22float2(h);
}

// --- pass A: per-block bucket histogram -> bh[blk][b] (no global atomics) --
__global__ __launch_bounds__(256) void histA_kernel(const int* __restrict__ ue,
                                                    const int* __restrict__ ie,
                                                    int* __restrict__ bh,
                                                    int E, int nu, int shift,
                                                    int NB, int NG) {
    __shared__ int lhist[NBMAX];
    int tid = threadIdx.x;
    for (int b = tid; b < NB; b += 256) lhist[b] = 0;
    __syncthreads();
    int g0 = blockIdx.x * ETG;
    int g1 = min(g0 + ETG, NG);
    for (int g = g0 + tid; g < g1; g += 256) {
        int e0 = g * 4;
        if (e0 + 3 < E) {
            nt_int4 u = __builtin_nontemporal_load((const nt_int4*)(ue + e0));
            nt_int4 v = __builtin_nontemporal_load((const nt_int4*)(ie + e0));
            atomicAdd(&lhist[(nu + v.x) >> shift], 1); atomicAdd(&lhist[u.x >> shift], 1);
            atomicAdd(&lhist[(nu + v.y) >> shift], 1); atomicAdd(&lhist[u.y >> shift], 1);
            atomicAdd(&lhist[(nu + v.z) >> shift], 1); atomicAdd(&lhist[u.z >> shift], 1);
            atomicAdd(&lhist[(nu + v.w) >> shift], 1); atomicAdd(&lhist[u.w >> shift], 1);
        } else {
            for (int e = e0; e < E; ++e) {
                atomicAdd(&lhist[(nu + ie[e]) >> shift], 1);
                atomicAdd(&lhist[ue[e] >> shift], 1);
            }
        }
    }
    __syncthreads();
    int* row = bh + (size_t)blockIdx.x * NB;
    for (int b = tid; b < NB; b += 256) row[b] = lhist[b];
}

// --- pass B1: column-wise exclusive scan over blocks -----------------------
// gb[blk][b] = sum_{blk'<blk} bh[blk'][b];  tot[b] = column total.
__global__ __launch_bounds__(64) void colscan_kernel(const int* __restrict__ bh,
                                                     int* __restrict__ gb,
                                                     int* __restrict__ tot,
                                                     int NBLK, int NB) {
    int b = blockIdx.x;
    int lane = threadIdx.x;
    int carry = 0;
    for (int i0 = 0; i0 < NBLK; i0 += 64) {
        int i = i0 + lane;
        int x = (i < NBLK) ? bh[(size_t)i * NB + b] : 0;
        int v = x;
        #pragma unroll
        for (int d = 1; d < 64; d <<= 1) {
            int o = __shfl_up(v, d, 64);
            if (lane >= d) v += o;
        }
        if (i < NBLK) gb[(size_t)i * NB + b] = v - x + carry;
        carry += __shfl(v, 63, 64);
    }
    if (lane == 0) tot[b] = carry;
}

// --- pass B2: exclusive scan over NB bucket totals -> pbase ----------------
__global__ __launch_bounds__(1024) void bscan_kernel(const int* __restrict__ tot,
                                                     int* __restrict__ pbase,
                                                     int NB, int twoE) {
    __shared__ int wsum[16];
    int t = threadIdx.x;
    int v0 = (t < NB) ? tot[t] : 0;
    int lane = t & 63, w = t >> 6;
    int v = v0;
    #pragma unroll
    for (int d = 1; d < 64; d <<= 1) {
        int o = __shfl_up(v, d, 64);
        if (lane >= d) v += o;
    }
    if (lane == 63) wsum[w] = v;
    __syncthreads();
    if (t == 0) {
        int r = 0;
        #pragma unroll
        for (int k = 0; k < 16; ++k) { int s = wsum[k]; wsum[k] = r; r += s; }
        pbase[NB] = twoE;
    }
    __syncthreads();
    int excl = (v - v0) + wsum[w];
    if (t < NB) pbase[t] = excl;
}

// --- pass C: place pairs at precomputed bases ------------------------------
// Reads its own hist row (2.4KB) instead of re-histogramming edges; LDS
// reorder into bucket-contiguous slots; coalesced run writes at
// pbase[b] + gb[blk][b]. No global atomics; packed pair = (dl<<18)|src.
__global__ __launch_bounds__(256) void place_kernel(const int* __restrict__ ue,
                                                    const int* __restrict__ ie,
                                                    const int* __restrict__ bh,
                                                    const int* __restrict__ gb,
                                                    const int* __restrict__ pbase,
                                                    int* __restrict__ pairs,
                                                    int E, int nu, int shift,
                                                    int NB, int NG) {
    __shared__ int slot[SLOTS];
    __shared__ int lhist[NBMAX];
    __shared__ int lcur[NBMAX];
    __shared__ int lbase[NBMAX];
    int blk = blockIdx.x, tid = threadIdx.x;
    for (int b = tid; b < NB; b += 256) {
        int c = bh[(size_t)blk * NB + b];
        lhist[b] = c;
        lbase[b] = pbase[b] + gb[(size_t)blk * NB + b];
    }
    __syncthreads();
    // exclusive scan of lhist -> lcur (wave 0, chunks of 64 with carry)
    if (tid < 64) {
        int carry = 0;
        for (int c = 0; c < NB; c += 64) {
            int idx = c + tid;
            int x = (idx < NB) ? lhist[idx] : 0;
            int v = x;
            #pragma unroll
            for (int d = 1; d < 64; d <<= 1) {
                int o = __shfl_up(v, d, 64);
                if (tid >= d) v += o;
            }
            if (idx < NB) lcur[idx] = v - x + carry;
            carry += __shfl(v, 63, 64);
        }
    }
    __syncthreads();
    int g0 = blk * ETG;
    int g1 = min(g0 + ETG, NG);
    int mask = (1 << shift) - 1;
    for (int g = g0 + tid; g < g1; g += 256) {
        int e0 = g * 4;
        if (e0 + 3 < E) {
            nt_int4 u = __builtin_nontemporal_load((const nt_int4*)(ue + e0));
            nt_int4 v = __builtin_nontemporal_load((const nt_int4*)(ie + e0));
            int uu[4] = {u.x, u.y, u.z, u.w};
            int vv[4] = {nu + v.x, nu + v.y, nu + v.z, nu + v.w};
            #pragma unroll
            for (int t = 0; t < 4; ++t) {
                int d = vv[t], s = uu[t];
                int p = atomicAdd(&lcur[d >> shift], 1);
                slot[p] = ((d & mask) << 18) | s;
                d = uu[t]; s = vv[t];
                p = atomicAdd(&lcur[d >> shift], 1);
                slot[p] = ((d & mask) << 18) | s;
            }
        } else {
            for (int e = e0; e < E; ++e) {
                int d = nu + ie[e], s = ue[e];
                int p = atomicAdd(&lcur[d >> shift], 1);
                slot[p] = ((d & mask) << 18) | s;
                d = ue[e]; s = nu + ie[e];
                p = atomicAdd(&lcur[d >> shift], 1);
                slot[p] = ((d & mask) << 18) | s;
            }
        }
    }
    __syncthreads();
    // write out runs: one wave per bucket, strided; coalesced within run
    int w = tid >> 6, lane = tid & 63;
    for (int b = w; b < NB; b += 4) {
        int c = lhist[b];
        if (!c) continue;
        int start = lcur[b] - c;   // cursor ended at start + c
        int gb0 = lbase[b];
        for (int i = lane; i < c; i += 64)
            pairs[gb0 + i] = slot[start + i];
    }
}

// --- pass D: per-bucket CSR build (deg hist + local scan + scatter) ------
__global__ __launch_bounds__(256) void build_kernel(const int* __restrict__ pairs,
                                                    const int* __restrict__ pbase,
                                                    int* __restrict__ offs,
                                                    float* __restrict__ dinv,
                                                    float* __restrict__ drt,
                                                    int* __restrict__ col,
                                                    int N, int shift, int NB, int twoE) {
    __shared__ int dcnt[512];
    __shared__ int ex[512];
    __shared__ int cur[512];
    int b = blockIdx.x, tid = threadIdx.x;
    int lo = b << shift;
    int n = min(1 << shift, N - lo);
    for (int i = tid; i < 512; i += 256) dcnt[i] = 0;
    __syncthreads();
    int pb = pbase[b];
    int cnt = pbase[b + 1] - pb;
    for (int i = tid; i < cnt; i += 256) {
        int p = pairs[pb + i];
        atomicAdd(&dcnt[p >> 18], 1);
    }
    __syncthreads();
    if (tid < 64) {
        int base = tid * 8;
        int loc[8]; int s = 0;
        #pragma unroll
        for (int k = 0; k < 8; ++k) { loc[k] = s; s += dcnt[base + k]; }
        int v = s;
        #pragma unroll
        for (int d = 1; d < 64; d <<= 1) {
            int o = __shfl_up(v, d, 64);
            if (tid >= d) v += o;
        }
        int excl = v - s;
        #pragma unroll
        for (int k = 0; k < 8; ++k) ex[base + k] = excl + loc[k];
    }
    __syncthreads();
    for (int i = tid; i < n; i += 256) {
        int c = pb + ex[i];
        cur[i] = c;
        offs[lo + i] = c;
        int d = dcnt[i];
        dinv[lo + i] = (d > 0) ? rsqrtf((float)d) : 0.0f;
        drt[lo + i]  = (d > 0) ? sqrtf((float)d)  : 0.0f;
    }
    if (b == NB - 1 && tid == 0) offs[N] = twoE;
    __syncthreads();
    for (int i = tid; i < cnt; i += 256) {
        int p = pairs[pb + i];
        int pos = atomicAdd(&cur[p >> 18], 1);
        col[pos] = p & 0x3FFFF;
    }
}

// --- batch-node marking / compaction -------------------------------------
__global__ void mark_kernel(const int* __restrict__ users, const int* __restrict__ items,
                            int* __restrict__ flag, int B, int nu) {
    int b = blockIdx.x * blockDim.x + threadIdx.x;
    if (b < B) {
        flag[users[b]] = 1;
        flag[nu + items[b]] = 1;
    }
}

__global__ void compact_kernel(const int* __restrict__ flag, int* __restrict__ list,
                               int* __restrict__ cnt, int N) {
    int n = blockIdx.x * blockDim.x + threadIdx.x;
    if (n < N && flag[n]) {
        int pos = atomicAdd(cnt, 1);
        list[pos] = n;
    }
}

// z init: za[n][k] = dinv[n] * x0[n][k], stored fp16. One thread = 8 k-dims.
__global__ void init_z_kernel(const float* __restrict__ Gu, const float* __restrict__ Gi,
                              const float* __restrict__ dinv,
                              __half* __restrict__ z, int nu, int N) {
    int id = blockIdx.x * blockDim.x + threadIdx.x;
    if (id < N * 8) {
        int n = id >> 3, q = id & 7;
        const float4* src = (n < nu) ? (const float4*)Gu : (const float4*)Gi;
        int j = (n < nu) ? n : n - nu;
        float4 a0 = src[(size_t)j * 16 + q * 2];
        float4 a1 = src[(size_t)j * 16 + q * 2 + 1];
        float w = dinv[n];
        uint4 o;
        o.x = pack2(a0.x * w, a0.y * w);
        o.y = pack2(a0.z * w, a0.w * w);
        o.z = pack2(a1.x * w, a1.y * w);
        o.w = pack2(a1.z * w, a1.w * w);
        ((uint4*)z)[id] = o;
    }
}

__global__ void init_bacc_kernel(const float* __restrict__ Gu, const float* __restrict__ Gi,
                                 const int* __restrict__ users, const int* __restrict__ items,
                                 float* __restrict__ baccU, float* __restrict__ baccI, int B) {
    int id = blockIdx.x * blockDim.x + threadIdx.x;  // B*16 float4 slots
    if (id < B * 16) {
        int b = id >> 4, q = id & 15;
        ((float4*)baccU)[id] = ((const float4*)Gu)[(size_t)users[b] * 16 + q];
        ((float4*)baccI)[id] = ((const float4*)Gi)[(size_t)items[b] * 16 + q];
    }
}

// One wave per destination row, vectorized gather with 2-deep load pipeline:
// lane = (neighbor-slot l>>3, k-quad l&7); each lane loads uint4 (8 halves);
// next iteration's load issues before the current one is consumed.
__global__ __launch_bounds__(256) void pull_kernel(const __half* __restrict__ z,
                                                   __half* __restrict__ zn,
                                                   const int* __restrict__ offs,
                                                   const int* __restrict__ col,
                                                   const float* __restrict__ dinv,
                                                   const int* __restrict__ rows,
                                                   const int* __restrict__ n_ptr, int N) {
    int wid = (blockIdx.x * blockDim.x + threadIdx.x) >> 6;
    int lane = threadIdx.x & 63;
    int nrows = rows ? *n_ptr : N;
    if (wid >= nrows) return;
    int r = rows ? rows[wid] : wid;
    int s = offs[r], e = offs[r + 1];
    int slot = lane >> 3;   // neighbor sub-slot 0..7
    int q    = lane & 7;    // k-quad: halves [8q, 8q+8)
    const uint4* zq = (const uint4*)z;
    float a0 = 0.f, a1 = 0.f, a2 = 0.f, a3 = 0.f;
    float a4 = 0.f, a5 = 0.f, a6 = 0.f, a7 = 0.f;
    for (int base = s; base < e; base += 64) {
        int idx = base + lane;
        int c = (idx < e) ? __builtin_nontemporal_load(col + idx) : 0;
        int n = min(64, e - base);
        int nfull = n & ~7;
        int j = 0;
        if (nfull > 0) {
            int cj = __shfl(c, slot);
            uint4 v = zq[(size_t)cj * 8 + q];
            for (j = 8; j < nfull; j += 8) {
                int cn = __shfl(c, j + slot);
                uint4 vn = zq[(size_t)cn * 8 + q];   // issue before consuming v
                float2 f0 = unpack2(v.x), f1 = unpack2(v.y);
                float2 f2 = unpack2(v.z), f3 = unpack2(v.w);
                a0 += f0.x; a1 += f0.y; a2 += f1.x; a3 += f1.y;
                a4 += f2.x; a5 += f2.y; a6 += f3.x; a7 += f3.y;
                v = vn;
            }
            float2 f0 = unpack2(v.x), f1 = unpack2(v.y);
            float2 f2 = unpack2(v.z), f3 = unpack2(v.w);
            a0 += f0.x; a1 += f0.y; a2 += f1.x; a3 += f1.y;
            a4 += f2.x; a5 += f2.y; a6 += f3.x; a7 += f3.y;
            j = nfull;
        }
        if (j < n) {
            int take = n - j;                       // 1..7 (wave-uniform)
            int cj = __shfl(c, j + (slot < take ? slot : 0));
            uint4 v = zq[(size_t)cj * 8 + q];
            if (slot < take) {
                float2 f0 = unpack2(v.x), f1 = unpack2(v.y);
                float2 f2 = unpack2(v.z), f3 = unpack2(v.w);
                a0 += f0.x; a1 += f0.y; a2 += f1.x; a3 += f1.y;
                a4 += f2.x; a5 += f2.y; a6 += f3.x; a7 += f3.y;
            }
        }
    }
    // reduce neighbor-slots: lanes {l, l^8, l^16, l^32} share k-quad q
    #pragma unroll
    for (int d = 8; d < 64; d <<= 1) {
        a0 += __shfl_xor(a0, d, 64); a1 += __shfl_xor(a1, d, 64);
        a2 += __shfl_xor(a2, d, 64); a3 += __shfl_xor(a3, d, 64);
        a4 += __shfl_xor(a4, d, 64); a5 += __shfl_xor(a5, d, 64);
        a6 += __shfl_xor(a6, d, 64); a7 += __shfl_xor(a7, d, 64);
    }
    if (slot == 0) {
        float w = dinv[r];
        float ww = w * w;
        uint4 o;
        o.x = pack2(a0 * ww, a1 * ww);
        o.y = pack2(a2 * ww, a3 * ww);
        o.z = pack2(a4 * ww, a5 * ww);
        o.w = pack2(a6 * ww, a7 * ww);
        ((uint4*)(zn + (size_t)r * WAVE))[q] = o;
    }
}

// bacc[b] += drt[node] * zn[node]; one thread = 8 k-dims. id over B*8.
__global__ void gather_acc_kernel(const __half* __restrict__ zn,
                                  const float* __restrict__ drt,
                                  const int* __restrict__ users, const int* __restrict__ items,
                                  float* __restrict__ baccU, float* __restrict__ baccI,
                                  int B, int nu) {
    int id = blockIdx.x * blockDim.x + threadIdx.x;
    if (id < B * 8) {
        int b = id >> 3, q = id & 7;
        int u = users[b], it = nu + items[b];
        float wu = drt[u], wi = drt[it];
        uint4 vu = ((const uint4*)(zn))[(size_t)u * 8 + q];
        uint4 vi = ((const uint4*)(zn))[(size_t)it * 8 + q];
        float2 u0 = unpack2(vu.x), u1 = unpack2(vu.y), u2 = unpack2(vu.z), u3 = unpack2(vu.w);
        float2 i0 = unpack2(vi.x), i1 = unpack2(vi.y), i2 = unpack2(vi.z), i3 = unpack2(vi.w);
        float4* bu = (float4*)baccU + (size_t)b * 16 + q * 2;
        float4* bi = (float4*)baccI + (size_t)b * 16 + q * 2;
        float4 a = bu[0];
        a.x += wu * u0.x; a.y += wu * u0.y; a.z += wu * u1.x; a.w += wu * u1.y;
        bu[0] = a;
        a = bu[1];
        a.x += wu * u2.x; a.y += wu * u2.y; a.z += wu * u3.x; a.w += wu * u3.y;
        bu[1] = a;
        a = bi[0];
        a.x += wi * i0.x; a.y += wi * i0.y; a.z += wi * i1.x; a.w += wi * i1.y;
        bi[0] = a;
        a = bi[1];
        a.x += wi * i2.x; a.y += wi * i2.y; a.z += wi * i3.x; a.w += wi * i3.y;
        bi[1] = a;
    }
}

// LDS-tiled fp32 GEMM + fused epilogue.
__global__ __launch_bounds__(256) void proj_out_kernel(const float* __restrict__ baccU,
                                                       const float* __restrict__ baccI,
                                                       const float* __restrict__ Tu,
                                                       const float* __restrict__ F,
                                                       const float* __restrict__ W,
                                                       const float* __restrict__ bvec,
                                                       const int* __restrict__ users,
                                                       const int* __restrict__ items,
                                                       float* __restrict__ out,
                                                       int B, float invL) {
    const int FEATn = 1024;
    __shared__ float Ft[2][32][64];
    __shared__ float Wt[2][32][64];

    int tid = threadIdx.x;
    int tx = tid & 15;        // col group (4 cols)
    int ty = tid >> 4;        // row group (4 rows)
    int r0 = blockIdx.x * 64;

    int lr = tid >> 2;                       // 0..63
    int lq = tid & 3;                        // quad group: local kk 4*lq and 4*lq+16
    int frow = min(r0 + lr, B - 1);
    const float* Fp = F + (size_t)items[frow] * FEATn + lq * 4;
    const float* Wp = W + (size_t)lr * FEATn + lq * 4;

    float4 fa0 = *(const float4*)(Fp);
    float4 fa1 = *(const float4*)(Fp + 16);
    float4 wa0 = *(const float4*)(Wp);
    float4 wa1 = *(const float4*)(Wp + 16);

    float acc[4][4] = {};

    for (int kt = 0; kt < 32; ++kt) {
        int buf = kt & 1;
        #pragma unroll
        for (int i = 0; i < 4; ++i) {
            Ft[buf][lq * 4 + i][lr]      = ((const float*)&fa0)[i];
            Ft[buf][lq * 4 + 16 + i][lr] = ((const float*)&fa1)[i];
            Wt[buf][lq * 4 + i][lr]      = ((const float*)&wa0)[i];
            Wt[buf][lq * 4 + 16 + i][lr] = ((const float*)&wa1)[i];
        }
        __syncthreads();
        if (kt < 31) {
            const float* fp = Fp + (kt + 1) * 32;
            const float* wp = Wp + (kt + 1) * 32;
            fa0 = *(const float4*)(fp);
            fa1 = *(const float4*)(fp + 16);
            wa0 = *(const float4*)(wp);
            wa1 = *(const float4*)(wp + 16);
        }
        #pragma unroll 8
        for (int kk = 0; kk < 32; ++kk) {
            float4 a = *(const float4*)&Ft[buf][kk][ty * 4];
            float4 b = *(const float4*)&Wt[buf][kk][tx * 4];
            acc[0][0] = fmaf(a.x, b.x, acc[0][0]);
            acc[0][1] = fmaf(a.x, b.y, acc[0][1]);
            acc[0][2] = fmaf(a.x, b.z, acc[0][2]);
            acc[0][3] = fmaf(a.x, b.w, acc[0][3]);
            acc[1][0] = fmaf(a.y, b.x, acc[1][0]);
            acc[1][1] = fmaf(a.y, b.y, acc[1][1]);
            acc[1][2] = fmaf(a.y, b.z, acc[1][2]);
            acc[1][3] = fmaf(a.y, b.w, acc[1][3]);
            acc[2][0] = fmaf(a.z, b.x, acc[2][0]);
            acc[2][1] = fmaf(a.z, b.y, acc[2][1]);
            acc[2][2] = fmaf(a.z, b.z, acc[2][2]);
            acc[2][3] = fmaf(a.z, b.w, acc[2][3]);
            acc[3][0] = fmaf(a.w, b.x, acc[3][0]);
            acc[3][1] = fmaf(a.w, b.y, acc[3][1]);
            acc[3][2] = fmaf(a.w, b.z, acc[3][2]);
            acc[3][3] = fmaf(a.w, b.w, acc[3][3]);
        }
    }

    float4 bb = *(const float4*)(bvec + tx * 4);
    float L2 = invL * invL;
    float res[4];
    #pragma unroll
    for (int r = 0; r < 4; ++r) {
        int gr = min(r0 + ty * 4 + r, B - 1);
        float pb0 = acc[r][0] + bb.x;
        float pb1 = acc[r][1] + bb.y;
        float pb2 = acc[r][2] + bb.z;
        float pb3 = acc[r][3] + bb.w;
        float s = pb0 * pb0 + pb1 * pb1 + pb2 * pb2 + pb3 * pb3;
        #pragma unroll
        for (int d = 1; d < 16; d <<= 1) s += __shfl_xor(s, d, 64);
        float inv = 1.0f / fmaxf(sqrtf(s), 1e-12f);
        int u = users[gr];
        float4 tu = *(const float4*)(Tu + (size_t)u * WAVE + tx * 4);
        float4 gu = *(const float4*)(baccU + (size_t)gr * WAVE + tx * 4);
        float4 gi = *(const float4*)(baccI + (size_t)gr * WAVE + tx * 4);
        float dsum = L2 * (gu.x * gi.x + gu.y * gi.y + gu.z * gi.z + gu.w * gi.w)
                   + inv * (tu.x * pb0 + tu.y * pb1 + tu.z * pb2 + tu.w * pb3);
        #pragma unroll
        for (int d = 1; d < 16; d <<= 1) dsum += __shfl_xor(dsum, d, 64);
        res[r] = dsum;
    }
    if (tx == 0) {
        #pragma unroll
        for (int r = 0; r < 4; ++r) {
            int gr = r0 + ty * 4 + r;
            if (gr < B) out[gr] = res[r];
        }
    }
}

extern "C" void kernel_launch(void* const* d_in, const int* in_sizes, int n_in,
                              void* d_out, int out_size, void* d_ws, size_t ws_size,
                              hipStream_t stream) {
    const float* Gu = (const float*)d_in[0];
    const float* Gi = (const float*)d_in[1];
    const float* Tu = (const float*)d_in[2];
    const float* F  = (const float*)d_in[3];
    const float* W  = (const float*)d_in[4];
    const float* bv = (const float*)d_in[5];
    const int* ue    = (const int*)d_in[6];
    const int* ie    = (const int*)d_in[7];
    const int* users = (const int*)d_in[8];
    const int* items = (const int*)d_in[9];
    float* out = (float*)d_out;

    const int K  = 64;
    const int nu = in_sizes[0] / K;
    const int ni = in_sizes[1] / K;
    const int N  = nu + ni;
    const int E  = in_sizes[6];
    const int B  = in_sizes[8];

    // bucket geometry: 256 nodes/bucket (shift 8) for this problem size
    int shift = 8;
    while (((N + (1 << shift) - 1) >> shift) > NBMAX) ++shift;
    const int NB = (N + (1 << shift) - 1) >> shift;

    const int NG   = (E + 3) / 4;            // int4 edge groups
    const int nbS  = (NG + ETG - 1) / ETG;   // hist/place blocks

    char* p = (char*)d_ws;
    auto alloc = [&](size_t bytes) -> void* {
        void* r = (void*)p;
        p += (bytes + 255) & ~(size_t)255;
        return r;
    };
    float* dinv   = (float*)alloc((size_t)N * 4);
    float* drt    = (float*)alloc((size_t)N * 4);
    int*   offs   = (int*)  alloc((size_t)(N + 1) * 4);
    int*   flags  = (int*)  alloc((size_t)N * 4);
    int*   col    = (int*)  alloc((size_t)2 * E * 4);
    __half* za    = (__half*)alloc((size_t)N * K * 2);
    __half* zb    = (__half*)alloc((size_t)N * K * 2);
    float* baccU  = (float*)alloc((size_t)B * K * 4);
    float* baccI  = (float*)alloc((size_t)B * K * 4);
    int*   list   = (int*)  alloc((size_t)2 * B * 4);
    int*   cnt    = (int*)  alloc(256);
    int*   bh     = (int*)  alloc((size_t)nbS * NB * 4);
    int*   gb     = (int*)  alloc((size_t)nbS * NB * 4);
    int*   tot    = (int*)  alloc((size_t)NBMAX * 4);
    int*   pbase  = (int*)  alloc((size_t)(NBMAX + 1) * 4);

    // packed pair staging (2E ints = 24MB) aliases za+zb (38.4MB fp16):
    // pairs are dead before init_z writes za.
    int* pairs = (int*)za;

    // graph build (deterministic: no global atomics anywhere)
    histA_kernel<<<nbS, 256, 0, stream>>>(ue, ie, bh, E, nu, shift, NB, NG);
    colscan_kernel<<<NB, 64, 0, stream>>>(bh, gb, tot, nbS, NB);
    bscan_kernel<<<1, 1024, 0, stream>>>(tot, pbase, NB, 2 * E);
    place_kernel<<<nbS, 256, 0, stream>>>(ue, ie, bh, gb, pbase, pairs,
                                          E, nu, shift, NB, NG);
    build_kernel<<<NB, 256, 0, stream>>>(pairs, pbase, offs, dinv, drt, col,
                                         N, shift, NB, 2 * E);

    // batch-node list
    hipMemsetAsync(flags, 0, (size_t)N * 4, stream);
    hipMemsetAsync(cnt, 0, 4, stream);
    mark_kernel<<<(B + 255) / 256, 256, 0, stream>>>(users, items, flags, B, nu);
    compact_kernel<<<(N + 255) / 256, 256, 0, stream>>>(flags, list, cnt, N);

    // init
    init_z_kernel<<<(N * 8 + 255) / 256, 256, 0, stream>>>(Gu, Gi, dinv, za, nu, N);
    init_bacc_kernel<<<(B * 16 + 255) / 256, 256, 0, stream>>>(Gu, Gi, users, items,
                                                               baccU, baccI, B);

    // layer 1 (full)
    pull_kernel<<<(N + 3) / 4, 256, 0, stream>>>(za, zb, offs, col, dinv,
                                                 nullptr, nullptr, N);
    gather_acc_kernel<<<(B * 8 + 255) / 256, 256, 0, stream>>>(zb, drt, users, items,
                                                               baccU, baccI, B, nu);
    // layer 2 (full)
    pull_kernel<<<(N + 3) / 4, 256, 0, stream>>>(zb, za, offs, col, dinv,
                                                 nullptr, nullptr, N);
    gather_acc_kernel<<<(B * 8 + 255) / 256, 256, 0, stream>>>(za, drt, users, items,
                                                               baccU, baccI, B, nu);
    // layer 3 (sparse: only unique batch rows)
    pull_kernel<<<(2 * B + 3) / 4, 256, 0, stream>>>(za, zb, offs, col, dinv,
                                                     list, cnt, N);
    gather_acc_kernel<<<(B * 8 + 255) / 256, 256, 0, stream>>>(zb, drt, users, items,
                                                               baccU, baccI, B, nu);

    // epilogue: LDS-tiled GEMM + fused norm/dots
    proj_out_kernel<<<(B + 63) / 64, 256, 0, stream>>>(baccU, baccI, Tu, F, W, bv,
                                                       users, items, out, B, 0.25f);
}

// Round 8
// 661.124 us; speedup vs baseline: 2.4107x; 1.0598x over previous
//
#include <hip/hip_runtime.h>
#include <hip/hip_bf16.h>
#include <hip/hip_fp16.h>

// LightGCN forward on MI355X.
// R12b: identical to R12 (previous round's bench died with an MI355X
//       container/broker failure before producing any measurement — no
//       kernel-attributable error). Resubmitting unchanged to get data.
// R12: dispatch-count surgery. R11 = 700us; top-5 is all harness re-poison
//      (fillBufferAligned 121us/iter, fixed). Budget: pulls ~207, build ~115,
//      proj ~45, small kernels + ~17 launch gaps ~105. Changes:
//      (1) layer-3 sparse path: iterate DIRECTLY over 2B batch entries
//          (wid<B -> users[wid] else items[wid-B]) -- each wid owns a distinct
//          bacc slot, so pull accumulates straight into baccU/baccI with
//          factor dinv[r] (drt*dinv^2 = dinv). Kills mark/compact/2 memsets/
//          gather_acc3 + the fp16 zn round-trip; ~12% dup work accepted.
//      (2) init_bacc fused into layer-1 gather (gather_init: bacc = G + drt*zn)
//          -- one less full pass over the 8MB bacc arrays.
//      Dispatches 17 -> 11. Graph build + pull core unchanged from R11.

#define WAVE 64
#define NBMAX 592   // max dst buckets; shift grows until NB <= NBMAX
#define SLOTS 14336 // pairs per scatter block (= 2 * 7168 edges)
#define ETG 1792    // int4 edge groups per scatter block (7168 edges)

typedef int nt_int4 __attribute__((ext_vector_type(4)));

__device__ __forceinline__ unsigned pack2(float lo, float hi) {
    __half2 h = __floats2half2_rn(lo, hi);
    return *(unsigned*)&h;
}
__device__ __forceinline__ float2 unpack2(unsigned u) {
    __half2 h = *(__half2*)&u;
    return __half22float2(h);
}

// --- pass A: per-block bucket histogram -> bh[blk][b] (no global atomics) --
__global__ __launch_bounds__(256) void histA_kernel(const int* __restrict__ ue,
                                                    const int* __restrict__ ie,
                                                    int* __restrict__ bh,
                                                    int E, int nu, int shift,
                                                    int NB, int NG) {
    __shared__ int lhist[NBMAX];
    int tid = threadIdx.x;
    for (int b = tid; b < NB; b += 256) lhist[b] = 0;
    __syncthreads();
    int g0 = blockIdx.x * ETG;
    int g1 = min(g0 + ETG, NG);
    for (int g = g0 + tid; g < g1; g += 256) {
        int e0 = g * 4;
        if (e0 + 3 < E) {
            nt_int4 u = __builtin_nontemporal_load((const nt_int4*)(ue + e0));
            nt_int4 v = __builtin_nontemporal_load((const nt_int4*)(ie + e0));
            atomicAdd(&lhist[(nu + v.x) >> shift], 1); atomicAdd(&lhist[u.x >> shift], 1);
            atomicAdd(&lhist[(nu + v.y) >> shift], 1); atomicAdd(&lhist[u.y >> shift], 1);
            atomicAdd(&lhist[(nu + v.z) >> shift], 1); atomicAdd(&lhist[u.z >> shift], 1);
            atomicAdd(&lhist[(nu + v.w) >> shift], 1); atomicAdd(&lhist[u.w >> shift], 1);
        } else {
            for (int e = e0; e < E; ++e) {
                atomicAdd(&lhist[(nu + ie[e]) >> shift], 1);
                atomicAdd(&lhist[ue[e] >> shift], 1);
            }
        }
    }
    __syncthreads();
    int* row = bh + (size_t)blockIdx.x * NB;
    for (int b = tid; b < NB; b += 256) row[b] = lhist[b];
}

// --- pass B1: column-wise exclusive scan over blocks -----------------------
__global__ __launch_bounds__(64) void colscan_kernel(const int* __restrict__ bh,
                                                     int* __restrict__ gb,
                                                     int* __restrict__ tot,
                                                     int NBLK, int NB) {
    int b = blockIdx.x;
    int lane = threadIdx.x;
    int carry = 0;
    for (int i0 = 0; i0 < NBLK; i0 += 64) {
        int i = i0 + lane;
        int x = (i < NBLK) ? bh[(size_t)i * NB + b] : 0;
        int v = x;
        #pragma unroll
        for (int d = 1; d < 64; d <<= 1) {
            int o = __shfl_up(v, d, 64);
            if (lane >= d) v += o;
        }
        if (i < NBLK) gb[(size_t)i * NB + b] = v - x + carry;
        carry += __shfl(v, 63, 64);
    }
    if (lane == 0) tot[b] = carry;
}

// --- pass B2: exclusive scan over NB bucket totals -> pbase ----------------
__global__ __launch_bounds__(1024) void bscan_kernel(const int* __restrict__ tot,
                                                     int* __restrict__ pbase,
                                                     int NB, int twoE) {
    __shared__ int wsum[16];
    int t = threadIdx.x;
    int v0 = (t < NB) ? tot[t] : 0;
    int lane = t & 63, w = t >> 6;
    int v = v0;
    #pragma unroll
    for (int d = 1; d < 64; d <<= 1) {
        int o = __shfl_up(v, d, 64);
        if (lane >= d) v += o;
    }
    if (lane == 63) wsum[w] = v;
    __syncthreads();
    if (t == 0) {
        int r = 0;
        #pragma unroll
        for (int k = 0; k < 16; ++k) { int s = wsum[k]; wsum[k] = r; r += s; }
        pbase[NB] = twoE;
    }
    __syncthreads();
    int excl = (v - v0) + wsum[w];
    if (t < NB) pbase[t] = excl;
}

// --- pass C: place pairs at precomputed bases ------------------------------
__global__ __launch_bounds__(256) void place_kernel(const int* __restrict__ ue,
                                                    const int* __restrict__ ie,
                                                    const int* __restrict__ bh,
                                                    const int* __restrict__ gb,
                                                    const int* __restrict__ pbase,
                                                    int* __restrict__ pairs,
                                                    int E, int nu, int shift,
                                                    int NB, int NG) {
    __shared__ int slot[SLOTS];
    __shared__ int lhist[NBMAX];
    __shared__ int lcur[NBMAX];
    __shared__ int lbase[NBMAX];
    int blk = blockIdx.x, tid = threadIdx.x;
    for (int b = tid; b < NB; b += 256) {
        int c = bh[(size_t)blk * NB + b];
        lhist[b] = c;
        lbase[b] = pbase[b] + gb[(size_t)blk * NB + b];
    }
    __syncthreads();
    if (tid < 64) {
        int carry = 0;
        for (int c = 0; c < NB; c += 64) {
            int idx = c + tid;
            int x = (idx < NB) ? lhist[idx] : 0;
            int v = x;
            #pragma unroll
            for (int d = 1; d < 64; d <<= 1) {
                int o = __shfl_up(v, d, 64);
                if (tid >= d) v += o;
            }
            if (idx < NB) lcur[idx] = v - x + carry;
            carry += __shfl(v, 63, 64);
        }
    }
    __syncthreads();
    int g0 = blk * ETG;
    int g1 = min(g0 + ETG, NG);
    int mask = (1 << shift) - 1;
    for (int g = g0 + tid; g < g1; g += 256) {
        int e0 = g * 4;
        if (e0 + 3 < E) {
            nt_int4 u = __builtin_nontemporal_load((const nt_int4*)(ue + e0));
            nt_int4 v = __builtin_nontemporal_load((const nt_int4*)(ie + e0));
            int uu[4] = {u.x, u.y, u.z, u.w};
            int vv[4] = {nu + v.x, nu + v.y, nu + v.z, nu + v.w};
            #pragma unroll
            for (int t = 0; t < 4; ++t) {
                int d = vv[t], s = uu[t];
                int p = atomicAdd(&lcur[d >> shift], 1);
                slot[p] = ((d & mask) << 18) | s;
                d = uu[t]; s = vv[t];
                p = atomicAdd(&lcur[d >> shift], 1);
                slot[p] = ((d & mask) << 18) | s;
            }
        } else {
            for (int e = e0; e < E; ++e) {
                int d = nu + ie[e], s = ue[e];
                int p = atomicAdd(&lcur[d >> shift], 1);
                slot[p] = ((d & mask) << 18) | s;
                d = ue[e]; s = nu + ie[e];
                p = atomicAdd(&lcur[d >> shift], 1);
                slot[p] = ((d & mask) << 18) | s;
            }
        }
    }
    __syncthreads();
    int w = tid >> 6, lane = tid & 63;
    for (int b = w; b < NB; b += 4) {
        int c = lhist[b];
        if (!c) continue;
        int start = lcur[b] - c;
        int gb0 = lbase[b];
        for (int i = lane; i < c; i += 64)
            pairs[gb0 + i] = slot[start + i];
    }
}

// --- pass D: per-bucket CSR build (deg hist + local scan + scatter) ------
__global__ __launch_bounds__(256) void build_kernel(const int* __restrict__ pairs,
                                                    const int* __restrict__ pbase,
                                                    int* __restrict__ offs,
                                                    float* __restrict__ dinv,
                                                    float* __restrict__ drt,
                                                    int* __restrict__ col,
                                                    int N, int shift, int NB, int twoE) {
    __shared__ int dcnt[512];
    __shared__ int ex[512];
    __shared__ int cur[512];
    int b = blockIdx.x, tid = threadIdx.x;
    int lo = b << shift;
    int n = min(1 << shift, N - lo);
    for (int i = tid; i < 512; i += 256) dcnt[i] = 0;
    __syncthreads();
    int pb = pbase[b];
    int cnt = pbase[b + 1] - pb;
    for (int i = tid; i < cnt; i += 256) {
        int p = pairs[pb + i];
        atomicAdd(&dcnt[p >> 18], 1);
    }
    __syncthreads();
    if (tid < 64) {
        int base = tid * 8;
        int loc[8]; int s = 0;
        #pragma unroll
        for (int k = 0; k < 8; ++k) { loc[k] = s; s += dcnt[base + k]; }
        int v = s;
        #pragma unroll
        for (int d = 1; d < 64; d <<= 1) {
            int o = __shfl_up(v, d, 64);
            if (tid >= d) v += o;
        }
        int excl = v - s;
        #pragma unroll
        for (int k = 0; k < 8; ++k) ex[base + k] = excl + loc[k];
    }
    __syncthreads();
    for (int i = tid; i < n; i += 256) {
        int c = pb + ex[i];
        cur[i] = c;
        offs[lo + i] = c;
        int d = dcnt[i];
        dinv[lo + i] = (d > 0) ? rsqrtf((float)d) : 0.0f;
        drt[lo + i]  = (d > 0) ? sqrtf((float)d)  : 0.0f;
    }
    if (b == NB - 1 && tid == 0) offs[N] = twoE;
    __syncthreads();
    for (int i = tid; i < cnt; i += 256) {
        int p = pairs[pb + i];
        int pos = atomicAdd(&cur[p >> 18], 1);
        col[pos] = p & 0x3FFFF;
    }
}

// z init: za[n][k] = dinv[n] * x0[n][k], stored fp16. One thread = 8 k-dims.
__global__ void init_z_kernel(const float* __restrict__ Gu, const float* __restrict__ Gi,
                              const float* __restrict__ dinv,
                              __half* __restrict__ z, int nu, int N) {
    int id = blockIdx.x * blockDim.x + threadIdx.x;
    if (id < N * 8) {
        int n = id >> 3, q = id & 7;
        const float4* src = (n < nu) ? (const float4*)Gu : (const float4*)Gi;
        int j = (n < nu) ? n : n - nu;
        float4 a0 = src[(size_t)j * 16 + q * 2];
        float4 a1 = src[(size_t)j * 16 + q * 2 + 1];
        float w = dinv[n];
        uint4 o;
        o.x = pack2(a0.x * w, a0.y * w);
        o.y = pack2(a0.z * w, a0.w * w);
        o.z = pack2(a1.x * w, a1.y * w);
        o.w = pack2(a1.z * w, a1.w * w);
        ((uint4*)z)[id] = o;
    }
}

// One wave per destination row, vectorized gather with 2-deep load pipeline.
__global__ __launch_bounds__(256) void pull_kernel(const __half* __restrict__ z,
                                                   __half* __restrict__ zn,
                                                   const int* __restrict__ offs,
                                                   const int* __restrict__ col,
                                                   const float* __restrict__ dinv,
                                                   int N) {
    int wid = (blockIdx.x * blockDim.x + threadIdx.x) >> 6;
    int lane = threadIdx.x & 63;
    if (wid >= N) return;
    int r = wid;
    int s = offs[r], e = offs[r + 1];
    int slot = lane >> 3;   // neighbor sub-slot 0..7
    int q    = lane & 7;    // k-quad: halves [8q, 8q+8)
    const uint4* zq = (const uint4*)z;
    float a0 = 0.f, a1 = 0.f, a2 = 0.f, a3 = 0.f;
    float a4 = 0.f, a5 = 0.f, a6 = 0.f, a7 = 0.f;
    for (int base = s; base < e; base += 64) {
        int idx = base + lane;
        int c = (idx < e) ? __builtin_nontemporal_load(col + idx) : 0;
        int n = min(64, e - base);
        int nfull = n & ~7;
        int j = 0;
        if (nfull > 0) {
            int cj = __shfl(c, slot);
            uint4 v = zq[(size_t)cj * 8 + q];
            for (j = 8; j < nfull; j += 8) {
                int cn = __shfl(c, j + slot);
                uint4 vn = zq[(size_t)cn * 8 + q];   // issue before consuming v
                float2 f0 = unpack2(v.x), f1 = unpack2(v.y);
                float2 f2 = unpack2(v.z), f3 = unpack2(v.w);
                a0 += f0.x; a1 += f0.y; a2 += f1.x; a3 += f1.y;
                a4 += f2.x; a5 += f2.y; a6 += f3.x; a7 += f3.y;
                v = vn;
            }
            float2 f0 = unpack2(v.x), f1 = unpack2(v.y);
            float2 f2 = unpack2(v.z), f3 = unpack2(v.w);
            a0 += f0.x; a1 += f0.y; a2 += f1.x; a3 += f1.y;
            a4 += f2.x; a5 += f2.y; a6 += f3.x; a7 += f3.y;
            j = nfull;
        }
        if (j < n) {
            int take = n - j;                       // 1..7 (wave-uniform)
            int cj = __shfl(c, j + (slot < take ? slot : 0));
            uint4 v = zq[(size_t)cj * 8 + q];
            if (slot < take) {
                float2 f0 = unpack2(v.x), f1 = unpack2(v.y);
                float2 f2 = unpack2(v.z), f3 = unpack2(v.w);
                a0 += f0.x; a1 += f0.y; a2 += f1.x; a3 += f1.y;
                a4 += f2.x; a5 += f2.y; a6 += f3.x; a7 += f3.y;
            }
        }
    }
    #pragma unroll
    for (int d = 8; d < 64; d <<= 1) {
        a0 += __shfl_xor(a0, d, 64); a1 += __shfl_xor(a1, d, 64);
        a2 += __shfl_xor(a2, d, 64); a3 += __shfl_xor(a3, d, 64);
        a4 += __shfl_xor(a4, d, 64); a5 += __shfl_xor(a5, d, 64);
        a6 += __shfl_xor(a6, d, 64); a7 += __shfl_xor(a7, d, 64);
    }
    if (slot == 0) {
        float w = dinv[r];
        float ww = w * w;
        uint4 o;
        o.x = pack2(a0 * ww, a1 * ww);
        o.y = pack2(a2 * ww, a3 * ww);
        o.z = pack2(a4 * ww, a5 * ww);
        o.w = pack2(a6 * ww, a7 * ww);
        ((uint4*)(zn + (size_t)r * WAVE))[q] = o;
    }
}

// Layer-3 fused pull: one wave per BATCH ENTRY (wid<B -> user, else item);
// accumulates x_3[r] = dinv[r] * sum(z2[c]) directly into this entry's bacc
// slot (distinct per wid -> no races, duplicates recompute harmlessly).
__global__ __launch_bounds__(256) void pull_batch_kernel(const __half* __restrict__ z,
                                                         const int* __restrict__ offs,
                                                         const int* __restrict__ col,
                                                         const float* __restrict__ dinv,
                                                         const int* __restrict__ users,
                                                         const int* __restrict__ items,
                                                         float* __restrict__ baccU,
                                                         float* __restrict__ baccI,
                                                         int B, int nu) {
    int wid = (blockIdx.x * blockDim.x + threadIdx.x) >> 6;
    int lane = threadIdx.x & 63;
    if (wid >= 2 * B) return;
    int r = (wid < B) ? users[wid] : nu + items[wid - B];
    int s = offs[r], e = offs[r + 1];
    int slot = lane >> 3;
    int q    = lane & 7;
    const uint4* zq = (const uint4*)z;
    float a0 = 0.f, a1 = 0.f, a2 = 0.f, a3 = 0.f;
    float a4 = 0.f, a5 = 0.f, a6 = 0.f, a7 = 0.f;
    for (int base = s; base < e; base += 64) {
        int idx = base + lane;
        int c = (idx < e) ? __builtin_nontemporal_load(col + idx) : 0;
        int n = min(64, e - base);
        int nfull = n & ~7;
        int j = 0;
        if (nfull > 0) {
            int cj = __shfl(c, slot);
            uint4 v = zq[(size_t)cj * 8 + q];
            for (j = 8; j < nfull; j += 8) {
                int cn = __shfl(c, j + slot);
                uint4 vn = zq[(size_t)cn * 8 + q];
                float2 f0 = unpack2(v.x), f1 = unpack2(v.y);
                float2 f2 = unpack2(v.z), f3 = unpack2(v.w);
                a0 += f0.x; a1 += f0.y; a2 += f1.x; a3 += f1.y;
                a4 += f2.x; a5 += f2.y; a6 += f3.x; a7 += f3.y;
                v = vn;
            }
            float2 f0 = unpack2(v.x), f1 = unpack2(v.y);
            float2 f2 = unpack2(v.z), f3 = unpack2(v.w);
            a0 += f0.x; a1 += f0.y; a2 += f1.x; a3 += f1.y;
            a4 += f2.x; a5 += f2.y; a6 += f3.x; a7 += f3.y;
            j = nfull;
        }
        if (j < n) {
            int take = n - j;
            int cj = __shfl(c, j + (slot < take ? slot : 0));
            uint4 v = zq[(size_t)cj * 8 + q];
            if (slot < take) {
                float2 f0 = unpack2(v.x), f1 = unpack2(v.y);
                float2 f2 = unpack2(v.z), f3 = unpack2(v.w);
                a0 += f0.x; a1 += f0.y; a2 += f1.x; a3 += f1.y;
                a4 += f2.x; a5 += f2.y; a6 += f3.x; a7 += f3.y;
            }
        }
    }
    #pragma unroll
    for (int d = 8; d < 64; d <<= 1) {
        a0 += __shfl_xor(a0, d, 64); a1 += __shfl_xor(a1, d, 64);
        a2 += __shfl_xor(a2, d, 64); a3 += __shfl_xor(a3, d, 64);
        a4 += __shfl_xor(a4, d, 64); a5 += __shfl_xor(a5, d, 64);
        a6 += __shfl_xor(a6, d, 64); a7 += __shfl_xor(a7, d, 64);
    }
    if (slot == 0) {
        float w = dinv[r];   // drt * dinv^2 = dinv
        float* bp = ((wid < B) ? (baccU + (size_t)wid * WAVE)
                               : (baccI + (size_t)(wid - B) * WAVE)) + q * 8;
        float4 b0 = *(float4*)bp;
        float4 b1 = *(float4*)(bp + 4);
        b0.x += w * a0; b0.y += w * a1; b0.z += w * a2; b0.w += w * a3;
        b1.x += w * a4; b1.y += w * a5; b1.z += w * a6; b1.w += w * a7;
        *(float4*)bp       = b0;
        *(float4*)(bp + 4) = b1;
    }
}

// Layer-1 gather fused with bacc init: bacc = G[node] + drt[node]*zn[node].
__global__ void gather_init_kernel(const __half* __restrict__ zn,
                                   const float* __restrict__ drt,
                                   const float* __restrict__ Gu,
                                   const float* __restrict__ Gi,
                                   const int* __restrict__ users,
                                   const int* __restrict__ items,
                                   float* __restrict__ baccU, float* __restrict__ baccI,
                                   int B, int nu) {
    int id = blockIdx.x * blockDim.x + threadIdx.x;
    if (id < B * 8) {
        int b = id >> 3, q = id & 7;
        int u = users[b], iti = items[b], it = nu + iti;
        float wu = drt[u], wi = drt[it];
        uint4 vu = ((const uint4*)(zn))[(size_t)u * 8 + q];
        uint4 vi = ((const uint4*)(zn))[(size_t)it * 8 + q];
        float2 u0 = unpack2(vu.x), u1 = unpack2(vu.y), u2 = unpack2(vu.z), u3 = unpack2(vu.w);
        float2 i0 = unpack2(vi.x), i1 = unpack2(vi.y), i2 = unpack2(vi.z), i3 = unpack2(vi.w);
        const float4* gu = (const float4*)Gu + (size_t)u * 16 + q * 2;
        const float4* gi = (const float4*)Gi + (size_t)iti * 16 + q * 2;
        float4* bu = (float4*)baccU + (size_t)b * 16 + q * 2;
        float4* bi = (float4*)baccI + (size_t)b * 16 + q * 2;
        float4 a = gu[0];
        a.x += wu * u0.x; a.y += wu * u0.y; a.z += wu * u1.x; a.w += wu * u1.y;
        bu[0] = a;
        a = gu[1];
        a.x += wu * u2.x; a.y += wu * u2.y; a.z += wu * u3.x; a.w += wu * u3.y;
        bu[1] = a;
        a = gi[0];
        a.x += wi * i0.x; a.y += wi * i0.y; a.z += wi * i1.x; a.w += wi * i1.y;
        bi[0] = a;
        a = gi[1];
        a.x += wi * i2.x; a.y += wi * i2.y; a.z += wi * i3.x; a.w += wi * i3.y;
        bi[1] = a;
    }
}

// Layer-2 gather: bacc += drt[node] * zn[node].
__global__ void gather_acc_kernel(const __half* __restrict__ zn,
                                  const float* __restrict__ drt,
                                  const int* __restrict__ users, const int* __restrict__ items,
                                  float* __restrict__ baccU, float* __restrict__ baccI,
                                  int B, int nu) {
    int id = blockIdx.x * blockDim.x + threadIdx.x;
    if (id < B * 8) {
        int b = id >> 3, q = id & 7;
        int u = users[b], it = nu + items[b];
        float wu = drt[u], wi = drt[it];
        uint4 vu = ((const uint4*)(zn))[(size_t)u * 8 + q];
        uint4 vi = ((const uint4*)(zn))[(size_t)it * 8 + q];
        float2 u0 = unpack2(vu.x), u1 = unpack2(vu.y), u2 = unpack2(vu.z), u3 = unpack2(vu.w);
        float2 i0 = unpack2(vi.x), i1 = unpack2(vi.y), i2 = unpack2(vi.z), i3 = unpack2(vi.w);
        float4* bu = (float4*)baccU + (size_t)b * 16 + q * 2;
        float4* bi = (float4*)baccI + (size_t)b * 16 + q * 2;
        float4 a = bu[0];
        a.x += wu * u0.x; a.y += wu * u0.y; a.z += wu * u1.x; a.w += wu * u1.y;
        bu[0] = a;
        a = bu[1];
        a.x += wu * u2.x; a.y += wu * u2.y; a.z += wu * u3.x; a.w += wu * u3.y;
        bu[1] = a;
        a = bi[0];
        a.x += wi * i0.x; a.y += wi * i0.y; a.z += wi * i1.x; a.w += wi * i1.y;
        bi[0] = a;
        a = bi[1];
        a.x += wi * i2.x; a.y += wi * i2.y; a.z += wi * i3.x; a.w += wi * i3.y;
        bi[1] = a;
    }
}

// LDS-tiled fp32 GEMM + fused epilogue.
__global__ __launch_bounds__(256) void proj_out_kernel(const float* __restrict__ baccU,
                                                       const float* __restrict__ baccI,
                                                       const float* __restrict__ Tu,
                                                       const float* __restrict__ F,
                                                       const float* __restrict__ W,
                                                       const float* __restrict__ bvec,
                                                       const int* __restrict__ users,
                                                       const int* __restrict__ items,
                                                       float* __restrict__ out,
                                                       int B, float invL) {
    const int FEATn = 1024;
    __shared__ float Ft[2][32][64];
    __shared__ float Wt[2][32][64];

    int tid = threadIdx.x;
    int tx = tid & 15;        // col group (4 cols)
    int ty = tid >> 4;        // row group (4 rows)
    int r0 = blockIdx.x * 64;

    int lr = tid >> 2;                       // 0..63
    int lq = tid & 3;                        // quad group: local kk 4*lq and 4*lq+16
    int frow = min(r0 + lr, B - 1);
    const float* Fp = F + (size_t)items[frow] * FEATn + lq * 4;
    const float* Wp = W + (size_t)lr * FEATn + lq * 4;

    float4 fa0 = *(const float4*)(Fp);
    float4 fa1 = *(const float4*)(Fp + 16);
    float4 wa0 = *(const float4*)(Wp);
    float4 wa1 = *(const float4*)(Wp + 16);

    float acc[4][4] = {};

    for (int kt = 0; kt < 32; ++kt) {
        int buf = kt & 1;
        #pragma unroll
        for (int i = 0; i < 4; ++i) {
            Ft[buf][lq * 4 + i][lr]      = ((const float*)&fa0)[i];
            Ft[buf][lq * 4 + 16 + i][lr] = ((const float*)&fa1)[i];
            Wt[buf][lq * 4 + i][lr]      = ((const float*)&wa0)[i];
            Wt[buf][lq * 4 + 16 + i][lr] = ((const float*)&wa1)[i];
        }
        __syncthreads();
        if (kt < 31) {
            const float* fp = Fp + (kt + 1) * 32;
            const float* wp = Wp + (kt + 1) * 32;
            fa0 = *(const float4*)(fp);
            fa1 = *(const float4*)(fp + 16);
            wa0 = *(const float4*)(wp);
            wa1 = *(const float4*)(wp + 16);
        }
        #pragma unroll 8
        for (int kk = 0; kk < 32; ++kk) {
            float4 a = *(const float4*)&Ft[buf][kk][ty * 4];
            float4 b = *(const float4*)&Wt[buf][kk][tx * 4];
            acc[0][0] = fmaf(a.x, b.x, acc[0][0]);
            acc[0][1] = fmaf(a.x, b.y, acc[0][1]);
            acc[0][2] = fmaf(a.x, b.z, acc[0][2]);
            acc[0][3] = fmaf(a.x, b.w, acc[0][3]);
            acc[1][0] = fmaf(a.y, b.x, acc[1][0]);
            acc[1][1] = fmaf(a.y, b.y, acc[1][1]);
            acc[1][2] = fmaf(a.y, b.z, acc[1][2]);
            acc[1][3] = fmaf(a.y, b.w, acc[1][3]);
            acc[2][0] = fmaf(a.z, b.x, acc[2][0]);
            acc[2][1] = fmaf(a.z, b.y, acc[2][1]);
            acc[2][2] = fmaf(a.z, b.z, acc[2][2]);
            acc[2][3] = fmaf(a.z, b.w, acc[2][3]);
            acc[3][0] = fmaf(a.w, b.x, acc[3][0]);
            acc[3][1] = fmaf(a.w, b.y, acc[3][1]);
            acc[3][2] = fmaf(a.w, b.z, acc[3][2]);
            acc[3][3] = fmaf(a.w, b.w, acc[3][3]);
        }
    }

    float4 bb = *(const float4*)(bvec + tx * 4);
    float L2 = invL * invL;
    float res[4];
    #pragma unroll
    for (int r = 0; r < 4; ++r) {
        int gr = min(r0 + ty * 4 + r, B - 1);
        float pb0 = acc[r][0] + bb.x;
        float pb1 = acc[r][1] + bb.y;
        float pb2 = acc[r][2] + bb.z;
        float pb3 = acc[r][3] + bb.w;
        float s = pb0 * pb0 + pb1 * pb1 + pb2 * pb2 + pb3 * pb3;
        #pragma unroll
        for (int d = 1; d < 16; d <<= 1) s += __shfl_xor(s, d, 64);
        float inv = 1.0f / fmaxf(sqrtf(s), 1e-12f);
        int u = users[gr];
        float4 tu = *(const float4*)(Tu + (size_t)u * WAVE + tx * 4);
        float4 gu = *(const float4*)(baccU + (size_t)gr * WAVE + tx * 4);
        float4 gi = *(const float4*)(baccI + (size_t)gr * WAVE + tx * 4);
        float dsum = L2 * (gu.x * gi.x + gu.y * gi.y + gu.z * gi.z + gu.w * gi.w)
                   + inv * (tu.x * pb0 + tu.y * pb1 + tu.z * pb2 + tu.w * pb3);
        #pragma unroll
        for (int d = 1; d < 16; d <<= 1) dsum += __shfl_xor(dsum, d, 64);
        res[r] = dsum;
    }
    if (tx == 0) {
        #pragma unroll
        for (int r = 0; r < 4; ++r) {
            int gr = r0 + ty * 4 + r;
            if (gr < B) out[gr] = res[r];
        }
    }
}

extern "C" void kernel_launch(void* const* d_in, const int* in_sizes, int n_in,
                              void* d_out, int out_size, void* d_ws, size_t ws_size,
                              hipStream_t stream) {
    const float* Gu = (const float*)d_in[0];
    const float* Gi = (const float*)d_in[1];
    const float* Tu = (const float*)d_in[2];
    const float* F  = (const float*)d_in[3];
    const float* W  = (const float*)d_in[4];
    const float* bv = (const float*)d_in[5];
    const int* ue    = (const int*)d_in[6];
    const int* ie    = (const int*)d_in[7];
    const int* users = (const int*)d_in[8];
    const int* items = (const int*)d_in[9];
    float* out = (float*)d_out;

    const int K  = 64;
    const int nu = in_sizes[0] / K;
    const int ni = in_sizes[1] / K;
    const int N  = nu + ni;
    const int E  = in_sizes[6];
    const int B  = in_sizes[8];

    // bucket geometry: 256 nodes/bucket (shift 8) for this problem size
    int shift = 8;
    while (((N + (1 << shift) - 1) >> shift) > NBMAX) ++shift;
    const int NB = (N + (1 << shift) - 1) >> shift;

    const int NG   = (E + 3) / 4;            // int4 edge groups
    const int nbS  = (NG + ETG - 1) / ETG;   // hist/place blocks

    char* p = (char*)d_ws;
    auto alloc = [&](size_t bytes) -> void* {
        void* r = (void*)p;
        p += (bytes + 255) & ~(size_t)255;
        return r;
    };
    float* dinv   = (float*)alloc((size_t)N * 4);
    float* drt    = (float*)alloc((size_t)N * 4);
    int*   offs   = (int*)  alloc((size_t)(N + 1) * 4);
    int*   col    = (int*)  alloc((size_t)2 * E * 4);
    __half* za    = (__half*)alloc((size_t)N * K * 2);
    __half* zb    = (__half*)alloc((size_t)N * K * 2);
    float* baccU  = (float*)alloc((size_t)B * K * 4);
    float* baccI  = (float*)alloc((size_t)B * K * 4);
    int*   bh     = (int*)  alloc((size_t)nbS * NB * 4);
    int*   gb     = (int*)  alloc((size_t)nbS * NB * 4);
    int*   tot    = (int*)  alloc((size_t)NBMAX * 4);
    int*   pbase  = (int*)  alloc((size_t)(NBMAX + 1) * 4);

    // packed pair staging (2E ints = 24MB) aliases za+zb (38.4MB fp16):
    // pairs are dead before init_z writes za.
    int* pairs = (int*)za;

    // graph build (deterministic: no global atomics anywhere)
    histA_kernel<<<nbS, 256, 0, stream>>>(ue, ie, bh, E, nu, shift, NB, NG);
    colscan_kernel<<<NB, 64, 0, stream>>>(bh, gb, tot, nbS, NB);
    bscan_kernel<<<1, 1024, 0, stream>>>(tot, pbase, NB, 2 * E);
    place_kernel<<<nbS, 256, 0, stream>>>(ue, ie, bh, gb, pbase, pairs,
                                          E, nu, shift, NB, NG);
    build_kernel<<<NB, 256, 0, stream>>>(pairs, pbase, offs, dinv, drt, col,
                                         N, shift, NB, 2 * E);

    // init z
    init_z_kernel<<<(N * 8 + 255) / 256, 256, 0, stream>>>(Gu, Gi, dinv, za, nu, N);

    // layer 1 (full) + fused bacc init
    pull_kernel<<<(N + 3) / 4, 256, 0, stream>>>(za, zb, offs, col, dinv, N);
    gather_init_kernel<<<(B * 8 + 255) / 256, 256, 0, stream>>>(zb, drt, Gu, Gi,
                                                                users, items,
                                                                baccU, baccI, B, nu);
    // layer 2 (full)
    pull_kernel<<<(N + 3) / 4, 256, 0, stream>>>(zb, za, offs, col, dinv, N);
    gather_acc_kernel<<<(B * 8 + 255) / 256, 256, 0, stream>>>(za, drt, users, items,
                                                               baccU, baccI, B, nu);
    // layer 3: fused sparse pull straight into bacc (one wave per batch entry)
    pull_batch_kernel<<<(2 * B + 3) / 4, 256, 0, stream>>>(za, offs, col, dinv,
                                                           users, items,
                                                           baccU, baccI, B, nu);

    // epilogue: LDS-tiled GEMM + fused norm/dots
    proj_out_kernel<<<(B + 63) / 64, 256, 0, stream>>>(baccU, baccI, Tu, F, W, bv,
                                                       users, items, out, B, 0.25f);
}